// Round 1
// baseline (1174.221 us; speedup 1.0000x reference)
//
#include <hip/hip_runtime.h>
#include <math.h>

// ---------------------------------------------------------------------------
// HodgeTorsionAttention: X->(Q,K,V) proj, softmax(QK^T/8 + phi*sin(giza*(j-i))),
// PV, out-proj. fp32 correctness-first baseline.
// B=2, S=2048, D=1024, H=16, hd=64.
// ---------------------------------------------------------------------------

// ---------------- torsion table: tab[i] = phi*sin(giza*(i-2047)), i<4096 ----
__global__ __launch_bounds__(256) void tor_table_k(float* __restrict__ tab) {
  int i = blockIdx.x * 256 + threadIdx.x;
  if (i < 4096) {
    double delta = (double)(i - 2047);
    double giza = 51.85 * M_PI / 180.0;
    tab[i] = (float)(1.618033988749895 * sin(giza * delta));
  }
}

// ---------------- GEMM: C[4096,1024] = A[4096,1024] @ W[1024,1024] + bias ---
// BM=BN=128, BK=16, 256 threads, 8x8 per thread.
__global__ __launch_bounds__(256) void gemm_bias_k(
    const float* __restrict__ A, const float* __restrict__ W,
    const float* __restrict__ bias, float* __restrict__ C)
{
  __shared__ float As[16][128];   // [k][m] (A staged transposed)
  __shared__ float Bs[16][128];   // [k][n]
  const int t  = threadIdx.x;
  const int tx = t & 15, ty = t >> 4;
  const int m0 = blockIdx.y << 7, n0 = blockIdx.x << 7;

  float acc[8][8];
#pragma unroll
  for (int i = 0; i < 8; ++i)
#pragma unroll
    for (int j = 0; j < 8; ++j) acc[i][j] = 0.f;

  for (int k0 = 0; k0 < 1024; k0 += 16) {
#pragma unroll
    for (int it = 0; it < 2; ++it) {
      int f = t + (it << 8);                 // f4 index 0..511
      int arow = f >> 2, kq = (f & 3) << 2;  // 4 f4 per A row
      float4 a = *(const float4*)&A[(size_t)(m0 + arow) * 1024u + (size_t)(k0 + kq)];
      As[kq + 0][arow] = a.x; As[kq + 1][arow] = a.y;
      As[kq + 2][arow] = a.z; As[kq + 3][arow] = a.w;
      int brow = f >> 5, nq = (f & 31) << 2; // 32 f4 per B row
      *(float4*)&Bs[brow][nq] =
          *(const float4*)&W[(size_t)(k0 + brow) * 1024u + (size_t)(n0 + nq)];
    }
    __syncthreads();
#pragma unroll
    for (int kk = 0; kk < 16; ++kk) {
      float4 a0 = *(const float4*)&As[kk][(ty << 2)];
      float4 a1 = *(const float4*)&As[kk][64 + (ty << 2)];
      float4 b0 = *(const float4*)&Bs[kk][(tx << 2)];
      float4 b1 = *(const float4*)&Bs[kk][64 + (tx << 2)];
      float av[8]  = {a0.x, a0.y, a0.z, a0.w, a1.x, a1.y, a1.z, a1.w};
      float bvv[8] = {b0.x, b0.y, b0.z, b0.w, b1.x, b1.y, b1.z, b1.w};
#pragma unroll
      for (int i = 0; i < 8; ++i)
#pragma unroll
        for (int j = 0; j < 8; ++j)
          acc[i][j] = fmaf(av[i], bvv[j], acc[i][j]);
    }
    __syncthreads();
  }

  float4 c0 = *(const float4*)&bias[n0 + (tx << 2)];
  float4 c1 = *(const float4*)&bias[n0 + 64 + (tx << 2)];
  float bb[8] = {c0.x, c0.y, c0.z, c0.w, c1.x, c1.y, c1.z, c1.w};
#pragma unroll
  for (int i = 0; i < 8; ++i) {
    int row = m0 + ((i < 4) ? ((ty << 2) + i) : (64 + (ty << 2) + i - 4));
    float4 o0 = make_float4(acc[i][0] + bb[0], acc[i][1] + bb[1],
                            acc[i][2] + bb[2], acc[i][3] + bb[3]);
    float4 o1 = make_float4(acc[i][4] + bb[4], acc[i][5] + bb[5],
                            acc[i][6] + bb[6], acc[i][7] + bb[7]);
    *(float4*)&C[(size_t)row * 1024u + (size_t)(n0 + (tx << 2))] = o0;
    *(float4*)&C[(size_t)row * 1024u + (size_t)(n0 + 64 + (tx << 2))] = o1;
  }
}

// ---------------- flash attention (fp32) ------------------------------------
// 128 q-rows per block, 128 threads = 16 row-groups x 8 col-groups,
// 8 rows x 8 cols (and 8 out-dims) per thread, 64-key tiles.
// K and V time-share one LDS buffer (static LDS stays < 64 KB).
__global__ __launch_bounds__(128, 1) void attn_k(
    const float* __restrict__ Q, const float* __restrict__ K,
    const float* __restrict__ V, const float* __restrict__ tab,
    float* __restrict__ O)
{
  __shared__ float Qt[64][128];   // [d][r], r = local q row
  __shared__ float KVs[64][68];   // K phase: [d][c]; V phase: [c][d]
  __shared__ float tors[192];

  const int t = threadIdx.x;
  const int j = t & 7;            // col-group (also out-dim group)
  const int i = t >> 3;           // row-group 0..15
  const int q0 = blockIdx.x << 7; // 16 q-tiles
  const int bh = blockIdx.y;      // 32 (b,h) pairs
  const size_t base = ((size_t)(bh >> 4) * 2048u) * 1024u + (size_t)(bh & 15) * 64u;

  // stage Q transposed (once per block)
#pragma unroll
  for (int it = 0; it < 16; ++it) {
    int f = t + (it << 7);                 // f4 index 0..2047
    int r = f >> 4, dq = (f & 15) << 2;
    float4 qv = *(const float4*)&Q[base + (size_t)(q0 + r) * 1024u + (size_t)dq];
    Qt[dq + 0][r] = qv.x; Qt[dq + 1][r] = qv.y;
    Qt[dq + 2][r] = qv.z; Qt[dq + 3][r] = qv.w;
  }

  float m_run[8], l_run[8], oacc[8][8];
#pragma unroll
  for (int ii = 0; ii < 8; ++ii) {
    m_run[ii] = -1e30f; l_run[ii] = 0.f;
#pragma unroll
    for (int jj = 0; jj < 8; ++jj) oacc[ii][jj] = 0.f;
  }

  for (int kc0 = 0; kc0 < 2048; kc0 += 64) {
    // stage K transposed [d][c] + torsion slice
#pragma unroll
    for (int it = 0; it < 8; ++it) {
      int f = t + (it << 7);               // f4 index 0..1023
      int c = f >> 4, dq = (f & 15) << 2;
      float4 kv = *(const float4*)&K[base + (size_t)(kc0 + c) * 1024u + (size_t)dq];
      KVs[dq + 0][c] = kv.x; KVs[dq + 1][c] = kv.y;
      KVs[dq + 2][c] = kv.z; KVs[dq + 3][c] = kv.w;
    }
    for (int x = t; x < 192; x += 128)
      tors[x] = tab[1920 + kc0 - q0 + x];  // tors[x] = tor(delta = kc0-q0+x-127)
    // prefetch V into registers (written to LDS after QK phase)
    float4 vreg[8];
#pragma unroll
    for (int it = 0; it < 8; ++it) {
      int f = t + (it << 7);
      int c = f >> 4, dq = (f & 15) << 2;
      vreg[it] = *(const float4*)&V[base + (size_t)(kc0 + c) * 1024u + (size_t)dq];
    }
    __syncthreads();

    // QK^T: s[8][8]
    float s[8][8];
#pragma unroll
    for (int ii = 0; ii < 8; ++ii)
#pragma unroll
      for (int jj = 0; jj < 8; ++jj) s[ii][jj] = 0.f;

    for (int d = 0; d < 64; ++d) {
      float4 qv0 = *(const float4*)&Qt[d][(i << 3)];
      float4 qv1 = *(const float4*)&Qt[d][(i << 3) + 4];
      float4 kv0 = *(const float4*)&KVs[d][(j << 3)];
      float4 kv1 = *(const float4*)&KVs[d][(j << 3) + 4];
      float qa[8] = {qv0.x, qv0.y, qv0.z, qv0.w, qv1.x, qv1.y, qv1.z, qv1.w};
      float ka[8] = {kv0.x, kv0.y, kv0.z, kv0.w, kv1.x, kv1.y, kv1.z, kv1.w};
#pragma unroll
      for (int ii = 0; ii < 8; ++ii)
#pragma unroll
        for (int jj = 0; jj < 8; ++jj)
          s[ii][jj] = fmaf(qa[ii], ka[jj], s[ii][jj]);
    }

    // scale + torsion + online softmax (row stats across 8 j-lanes)
#pragma unroll
    for (int ii = 0; ii < 8; ++ii) {
      int ir = (i << 3) + ii;
#pragma unroll
      for (int jj = 0; jj < 8; ++jj)
        s[ii][jj] = fmaf(s[ii][jj], 0.125f, tors[127 + (j << 3) + jj - ir]);
      float mloc = s[ii][0];
#pragma unroll
      for (int jj = 1; jj < 8; ++jj) mloc = fmaxf(mloc, s[ii][jj]);
      mloc = fmaxf(mloc, __shfl_xor(mloc, 1, 64));
      mloc = fmaxf(mloc, __shfl_xor(mloc, 2, 64));
      mloc = fmaxf(mloc, __shfl_xor(mloc, 4, 64));
      float mnew = fmaxf(m_run[ii], mloc);
      float alpha = __expf(m_run[ii] - mnew);
      float lsum = 0.f;
#pragma unroll
      for (int jj = 0; jj < 8; ++jj) {
        float p = __expf(s[ii][jj] - mnew);
        s[ii][jj] = p; lsum += p;
      }
      lsum += __shfl_xor(lsum, 1, 64);
      lsum += __shfl_xor(lsum, 2, 64);
      lsum += __shfl_xor(lsum, 4, 64);
      l_run[ii] = l_run[ii] * alpha + lsum;
      m_run[ii] = mnew;
#pragma unroll
      for (int jj = 0; jj < 8; ++jj) oacc[ii][jj] *= alpha;
    }
    __syncthreads();   // done reading K from KVs

    // write prefetched V into KVs as [c][d]
#pragma unroll
    for (int it = 0; it < 8; ++it) {
      int f = t + (it << 7);
      int c = f >> 4, dq = (f & 15) << 2;
      *(float4*)&KVs[c][dq] = vreg[it];
    }
    __syncthreads();

    // PV: oacc[r][d] += p[r][c] * V[c][d]; p broadcast via shfl from owner lane
    for (int c1 = 0; c1 < 8; ++c1) {
      int src = ((i & 7) << 3) | c1;       // owner lane of cols c1*8..+8 in this row-group
#pragma unroll
      for (int cc = 0; cc < 8; ++cc) {
        int c = (c1 << 3) | cc;
        float4 v0 = *(const float4*)&KVs[c][(j << 3)];
        float4 v1 = *(const float4*)&KVs[c][(j << 3) + 4];
#pragma unroll
        for (int ii = 0; ii < 8; ++ii) {
          float prc = __shfl(s[ii][cc], src, 64);
          oacc[ii][0] = fmaf(prc, v0.x, oacc[ii][0]);
          oacc[ii][1] = fmaf(prc, v0.y, oacc[ii][1]);
          oacc[ii][2] = fmaf(prc, v0.z, oacc[ii][2]);
          oacc[ii][3] = fmaf(prc, v0.w, oacc[ii][3]);
          oacc[ii][4] = fmaf(prc, v1.x, oacc[ii][4]);
          oacc[ii][5] = fmaf(prc, v1.y, oacc[ii][5]);
          oacc[ii][6] = fmaf(prc, v1.z, oacc[ii][6]);
          oacc[ii][7] = fmaf(prc, v1.w, oacc[ii][7]);
        }
      }
    }
    __syncthreads();   // done reading V before next-tile K staging
  }

  // epilogue: normalize and store merged-head layout [(b*S+s)*D + h*64 + d]
#pragma unroll
  for (int ii = 0; ii < 8; ++ii) {
    float inv = 1.f / l_run[ii];
    int r = q0 + (i << 3) + ii;
    float4 o0 = make_float4(oacc[ii][0] * inv, oacc[ii][1] * inv,
                            oacc[ii][2] * inv, oacc[ii][3] * inv);
    float4 o1 = make_float4(oacc[ii][4] * inv, oacc[ii][5] * inv,
                            oacc[ii][6] * inv, oacc[ii][7] * inv);
    *(float4*)&O[base + (size_t)r * 1024u + (size_t)(j << 3)] = o0;
    *(float4*)&O[base + (size_t)r * 1024u + (size_t)((j << 3) + 4)] = o1;
  }
}

// ---------------------------------------------------------------------------
extern "C" void kernel_launch(void* const* d_in, const int* in_sizes, int n_in,
                              void* d_out, int out_size, void* d_ws, size_t ws_size,
                              hipStream_t stream) {
  (void)in_sizes; (void)n_in; (void)out_size; (void)ws_size;
  const float* hs = (const float*)d_in[0];
  const float* Wq = (const float*)d_in[1];
  const float* bq = (const float*)d_in[2];
  const float* Wk = (const float*)d_in[3];
  const float* bk = (const float*)d_in[4];
  const float* Wv = (const float*)d_in[5];
  const float* bv = (const float*)d_in[6];
  const float* Wo = (const float*)d_in[7];
  const float* bo = (const float*)d_in[8];
  float* out = (float*)d_out;

  // workspace layout (floats): tab[4096] | Q | K | V | attn_out  (~64.02 MB)
  float* ws  = (float*)d_ws;
  float* tab = ws;
  float* Qb  = ws + 4096;
  float* Kb  = Qb + 4194304;
  float* Vb  = Kb + 4194304;
  float* Ab  = Vb + 4194304;

  tor_table_k<<<16, 256, 0, stream>>>(tab);

  dim3 gg(8, 32);  // N/128 x M/128
  gemm_bias_k<<<gg, 256, 0, stream>>>(hs, Wq, bq, Qb);
  gemm_bias_k<<<gg, 256, 0, stream>>>(hs, Wk, bk, Kb);
  gemm_bias_k<<<gg, 256, 0, stream>>>(hs, Wv, bv, Vb);

  attn_k<<<dim3(16, 32), 128, 0, stream>>>(Qb, Kb, Vb, tab, Ab);

  gemm_bias_k<<<gg, 256, 0, stream>>>(Ab, Wo, bo, out);
}

// Round 6
// 752.323 us; speedup vs baseline: 1.5608x; 1.5608x over previous
//
#include <hip/hip_runtime.h>
#include <math.h>

// ---------------------------------------------------------------------------
// HodgeTorsionAttention. R2: fp32 GEMMs (bf16 epilogue for QKV) + bf16 MFMA
// flash attention. B=2, S=2048, D=1024, H=16, hd=64.
// ---------------------------------------------------------------------------

typedef __attribute__((ext_vector_type(8))) short bf16x8;   // 8 bf16 = 4 VGPR
typedef __attribute__((ext_vector_type(4))) float f32x4;    // MFMA acc

__device__ __forceinline__ unsigned short f2bf(float f) {   // RNE f32->bf16
  unsigned u = __float_as_uint(f);
  unsigned r = (u + 0x7FFFu + ((u >> 16) & 1u)) >> 16;
  return (unsigned short)r;
}

// ---------------- torsion table: tab[i] = phi*sin(giza*(i-2047)), i<4096 ----
__global__ __launch_bounds__(256) void tor_table_k(float* __restrict__ tab) {
  int i = blockIdx.x * 256 + threadIdx.x;
  if (i < 4096) {
    double delta = (double)(i - 2047);
    double giza = 51.85 * M_PI / 180.0;
    tab[i] = (float)(1.618033988749895 * sin(giza * delta));
  }
}

// ---------------- GEMM: C[4096,1024] = A[4096,1024] @ W[1024,1024] + bias ---
// BM=BN=128, BK=16, 256 threads, 8x8 per thread.
// MODE 0: fp32 merged [tok][1024]   (final out-proj)
// MODE 1: bf16 head-split [bh][tok][64]          (Q, K)
// MODE 2: bf16 head-split transposed [bh][64][tok]  (V)
template <int MODE>
__global__ __launch_bounds__(256) void gemm_bias_k(
    const float* __restrict__ A, const float* __restrict__ W,
    const float* __restrict__ bias, float* __restrict__ C,
    unsigned short* __restrict__ Cb)
{
  __shared__ float As[16][128];   // [k][m]
  __shared__ float Bs[16][128];   // [k][n]
  const int t  = threadIdx.x;
  const int tx = t & 15, ty = t >> 4;
  const int m0 = blockIdx.y << 7, n0 = blockIdx.x << 7;

  float acc[8][8];
#pragma unroll
  for (int i = 0; i < 8; ++i)
#pragma unroll
    for (int j = 0; j < 8; ++j) acc[i][j] = 0.f;

  for (int k0 = 0; k0 < 1024; k0 += 16) {
#pragma unroll
    for (int it = 0; it < 2; ++it) {
      int f = t + (it << 8);                 // f4 index 0..511
      int arow = f >> 2, kq = (f & 3) << 2;  // 4 f4 per A row
      float4 a = *(const float4*)&A[(size_t)(m0 + arow) * 1024u + (size_t)(k0 + kq)];
      As[kq + 0][arow] = a.x; As[kq + 1][arow] = a.y;
      As[kq + 2][arow] = a.z; As[kq + 3][arow] = a.w;
      int brow = f >> 5, nq = (f & 31) << 2; // 32 f4 per B row
      *(float4*)&Bs[brow][nq] =
          *(const float4*)&W[(size_t)(k0 + brow) * 1024u + (size_t)(n0 + nq)];
    }
    __syncthreads();
#pragma unroll
    for (int kk = 0; kk < 16; ++kk) {
      float4 a0 = *(const float4*)&As[kk][(ty << 2)];
      float4 a1 = *(const float4*)&As[kk][64 + (ty << 2)];
      float4 b0 = *(const float4*)&Bs[kk][(tx << 2)];
      float4 b1 = *(const float4*)&Bs[kk][64 + (tx << 2)];
      float av[8]  = {a0.x, a0.y, a0.z, a0.w, a1.x, a1.y, a1.z, a1.w};
      float bvv[8] = {b0.x, b0.y, b0.z, b0.w, b1.x, b1.y, b1.z, b1.w};
#pragma unroll
      for (int i = 0; i < 8; ++i)
#pragma unroll
        for (int j = 0; j < 8; ++j)
          acc[i][j] = fmaf(av[i], bvv[j], acc[i][j]);
    }
    __syncthreads();
  }

  float4 c0 = *(const float4*)&bias[n0 + (tx << 2)];
  float4 c1 = *(const float4*)&bias[n0 + 64 + (tx << 2)];
  float bb[8] = {c0.x, c0.y, c0.z, c0.w, c1.x, c1.y, c1.z, c1.w};

  if (MODE == 0) {
#pragma unroll
    for (int i = 0; i < 8; ++i) {
      int row = m0 + ((i < 4) ? ((ty << 2) + i) : (64 + (ty << 2) + i - 4));
      float4 o0 = make_float4(acc[i][0] + bb[0], acc[i][1] + bb[1],
                              acc[i][2] + bb[2], acc[i][3] + bb[3]);
      float4 o1 = make_float4(acc[i][4] + bb[4], acc[i][5] + bb[5],
                              acc[i][6] + bb[6], acc[i][7] + bb[7]);
      *(float4*)&C[(size_t)row * 1024u + (size_t)(n0 + (tx << 2))] = o0;
      *(float4*)&C[(size_t)row * 1024u + (size_t)(n0 + 64 + (tx << 2))] = o1;
    }
  } else if (MODE == 1) {
#pragma unroll
    for (int i = 0; i < 8; ++i) {
      int row = m0 + ((i < 4) ? ((ty << 2) + i) : (64 + (ty << 2) + i - 4));
      int bsel = row >> 11, tok = row & 2047;
      int n1 = n0 + (tx << 2);
      unsigned short* p1 = &Cb[(size_t)((bsel << 4) + (n1 >> 6)) * 131072u +
                               (size_t)tok * 64u + (size_t)(n1 & 63)];
      *(ushort4*)p1 = make_ushort4(f2bf(acc[i][0] + bb[0]), f2bf(acc[i][1] + bb[1]),
                                   f2bf(acc[i][2] + bb[2]), f2bf(acc[i][3] + bb[3]));
      int n2 = n1 + 64;
      unsigned short* p2 = &Cb[(size_t)((bsel << 4) + (n2 >> 6)) * 131072u +
                               (size_t)tok * 64u + (size_t)(n2 & 63)];
      *(ushort4*)p2 = make_ushort4(f2bf(acc[i][4] + bb[4]), f2bf(acc[i][5] + bb[5]),
                                   f2bf(acc[i][6] + bb[6]), f2bf(acc[i][7] + bb[7]));
    }
  } else {  // MODE 2: V transposed [bh][64][2048]
#pragma unroll
    for (int j = 0; j < 8; ++j) {
      int n = (j < 4) ? (n0 + (tx << 2) + j) : (n0 + 64 + (tx << 2) + (j - 4));
      int h = n >> 6, d = n & 63;
      int rowa = m0 + (ty << 2);
      int ba = rowa >> 11, toka = rowa & 2047;
      unsigned short* pa = &Cb[(size_t)((ba << 4) + h) * 131072u +
                               (size_t)d * 2048u + (size_t)toka];
      *(ushort4*)pa = make_ushort4(f2bf(acc[0][j] + bb[j]), f2bf(acc[1][j] + bb[j]),
                                   f2bf(acc[2][j] + bb[j]), f2bf(acc[3][j] + bb[j]));
      int rowb = m0 + 64 + (ty << 2);
      int bb2 = rowb >> 11, tokb = rowb & 2047;
      unsigned short* pb = &Cb[(size_t)((bb2 << 4) + h) * 131072u +
                               (size_t)d * 2048u + (size_t)tokb];
      *(ushort4*)pb = make_ushort4(f2bf(acc[4][j] + bb[j]), f2bf(acc[5][j] + bb[j]),
                                   f2bf(acc[6][j] + bb[j]), f2bf(acc[7][j] + bb[j]));
    }
  }
}

// ---------------- bf16 MFMA flash attention ---------------------------------
// grid (16 q-tiles, 32 bh), 256 threads = 4 waves, 32 q-rows/wave.
// Q in registers; K/Vt XOR-swizzled LDS, double-buffered, T14 reg staging;
// per-wave private P tile in LDS (no cross-wave P use -> no extra barrier).
// MFMA 16x16x32 bf16. C/D layout: col=lane&15, row=(lane>>4)*4+reg (m89).
__global__ __launch_bounds__(256) void attn_mfma_k(
    const unsigned short* __restrict__ Qb, const unsigned short* __restrict__ Kb,
    const unsigned short* __restrict__ Vtg, const float* __restrict__ tab,
    float* __restrict__ O)
{
  __shared__ unsigned short Ks[2][4096];  // [64 key][64 dim] swizzled, 8KB ea
  __shared__ unsigned short Vs[2][4096];  // [64 dim][64 key] swizzled
  __shared__ unsigned short Ps[4][2048];  // per-wave [32 q][64 key] swizzled
  __shared__ float tors[2176];

  const int t  = threadIdx.x;
  const int l  = t & 63;
  const int wq = t >> 6;
  const int l15 = l & 15, lg = l >> 4;
  const int q0 = blockIdx.x << 7;
  const int bh = blockIdx.y;

  // torsion slice for this block: tors[i] = tab[1920 - q0 + i]; index range
  // needed: 127 + kc + key - ql  in [0, 2175); tab idx stays in [0,4096). G2.
  for (int x = t; x < 2176; x += 256) tors[x] = tab[1920 - q0 + x];

  const unsigned short* Qp = Qb + (size_t)bh * 131072u;
  const char* Kpanel = (const char*)(Kb  + (size_t)bh * 131072u);
  const char* Vpanel = (const char*)(Vtg + (size_t)bh * 131072u);

  // Q fragments (A-operand): row = l&15 (+16*mf), k-dims = lg*8.. (+32*kt)
  bf16x8 qf[2][2];
#pragma unroll
  for (int mf = 0; mf < 2; ++mf)
#pragma unroll
    for (int kt = 0; kt < 2; ++kt) {
      int tok = q0 + wq * 32 + mf * 16 + l15;
      qf[mf][kt] = *(const bf16x8*)&Qp[(size_t)tok * 64u + (size_t)(kt * 32 + lg * 8)];
    }

  f32x4 oacc[2][4];
  float m_run[2][4], l_run[2][4];
#pragma unroll
  for (int mf = 0; mf < 2; ++mf)
#pragma unroll
    for (int r = 0; r < 4; ++r) {
      m_run[mf][r] = -1e30f; l_run[mf][r] = 0.f;
      f32x4 z = {0.f, 0.f, 0.f, 0.f};
      oacc[mf][r] = z;
    }

  // staging geometry: this thread handles logical bytes sb, sb+1024 of the
  // 8KB tile (wave w -> chunks 2w, 2w+1). LDS dest swizzle: row-major 128B
  // rows, byte ^= (row&7)<<4 (G4: stride-128B rows are 16-way conflicts raw).
  const int sb    = (wq * 2) * 1024 + l * 16;
  const int srow0 = sb >> 7,          scol0 = sb & 127;
  const int srow1 = (sb + 1024) >> 7, scol1 = (sb + 1024) & 127;
  const int sdst0 = srow0 * 128 + (scol0 ^ ((srow0 & 7) << 4));
  const int sdst1 = srow1 * 128 + (scol1 ^ ((srow1 & 7) << 4));

  int4 kreg0, kreg1, vreg0, vreg1;
  // prologue: stage tile 0
  kreg0 = *(const int4*)(Kpanel + sb);
  kreg1 = *(const int4*)(Kpanel + sb + 1024);
  vreg0 = *(const int4*)(Vpanel + (size_t)srow0 * 4096u + (size_t)scol0);
  vreg1 = *(const int4*)(Vpanel + (size_t)srow1 * 4096u + (size_t)scol1);
  *(int4*)((char*)Ks[0] + sdst0) = kreg0;
  *(int4*)((char*)Ks[0] + sdst1) = kreg1;
  *(int4*)((char*)Vs[0] + sdst0) = vreg0;
  *(int4*)((char*)Vs[0] + sdst1) = vreg1;
  __syncthreads();

  unsigned short* Pw = Ps[wq];

  for (int tt = 0; tt < 32; ++tt) {
    const int buf = tt & 1;
    const int kc  = tt << 6;

    // T14 issue-early: next tile's global loads before compute
    if (tt < 31) {
      const char* kp = Kpanel + (tt + 1) * 8192;
      kreg0 = *(const int4*)(kp + sb);
      kreg1 = *(const int4*)(kp + sb + 1024);
      const char* vp = Vpanel + (tt + 1) * 128;
      vreg0 = *(const int4*)(vp + (size_t)srow0 * 4096u + (size_t)scol0);
      vreg1 = *(const int4*)(vp + (size_t)srow1 * 4096u + (size_t)scol1);
    }

    // ---- QK^T: S[32 q][64 key] per wave
    f32x4 sacc[2][4];
#pragma unroll
    for (int mf = 0; mf < 2; ++mf)
#pragma unroll
      for (int nf = 0; nf < 4; ++nf) {
        f32x4 z = {0.f, 0.f, 0.f, 0.f};
        sacc[mf][nf] = z;
      }
    const char* Kl = (const char*)Ks[buf];
#pragma unroll
    for (int kt = 0; kt < 2; ++kt) {
#pragma unroll
      for (int nf = 0; nf < 4; ++nf) {
        int key = l15 + nf * 16;
        bf16x8 kf = *(const bf16x8*)(Kl + (key << 7) +
                     (((kt << 6) + (lg << 4)) ^ ((key & 7) << 4)));
        sacc[0][nf] = __builtin_amdgcn_mfma_f32_16x16x32_bf16(qf[0][kt], kf, sacc[0][nf], 0, 0, 0);
        sacc[1][nf] = __builtin_amdgcn_mfma_f32_16x16x32_bf16(qf[1][kt], kf, sacc[1][nf], 0, 0, 0);
      }
    }

    // ---- scale + torsion + online softmax; P -> per-wave LDS (bf16)
#pragma unroll
    for (int mf = 0; mf < 2; ++mf)
#pragma unroll
      for (int r = 0; r < 4; ++r) {
        int ql = wq * 32 + mf * 16 + lg * 4 + r;   // q row in block
        int tb = 127 + kc + l15 - ql;
        float x0 = fmaf(sacc[mf][0][r], 0.125f, tors[tb]);
        float x1 = fmaf(sacc[mf][1][r], 0.125f, tors[tb + 16]);
        float x2 = fmaf(sacc[mf][2][r], 0.125f, tors[tb + 32]);
        float x3 = fmaf(sacc[mf][3][r], 0.125f, tors[tb + 48]);
        float mx = fmaxf(fmaxf(x0, x1), fmaxf(x2, x3));
        mx = fmaxf(mx, __shfl_xor(mx, 1, 64));
        mx = fmaxf(mx, __shfl_xor(mx, 2, 64));
        mx = fmaxf(mx, __shfl_xor(mx, 4, 64));
        mx = fmaxf(mx, __shfl_xor(mx, 8, 64));
        float mold = m_run[mf][r];
        float mnew = fmaxf(mold, mx);
        float alpha = __expf(mold - mnew);
        float p0 = __expf(x0 - mnew);
        float p1 = __expf(x1 - mnew);
        float p2 = __expf(x2 - mnew);
        float p3 = __expf(x3 - mnew);
        float ls = (p0 + p1) + (p2 + p3);
        ls += __shfl_xor(ls, 1, 64);
        ls += __shfl_xor(ls, 2, 64);
        ls += __shfl_xor(ls, 4, 64);
        ls += __shfl_xor(ls, 8, 64);
        m_run[mf][r] = mnew;
        l_run[mf][r] = l_run[mf][r] * alpha + ls;
        oacc[mf][0][r] *= alpha;
        oacc[mf][1][r] *= alpha;
        oacc[mf][2][r] *= alpha;
        oacc[mf][3][r] *= alpha;
        int qrow = mf * 16 + lg * 4 + r;           // q row within wave tile
        int rb = qrow << 7, sw = (qrow & 7) << 4;
        *(unsigned short*)((char*)Pw + rb + (((l15 << 1) +  0) ^ sw)) = f2bf(p0);
        *(unsigned short*)((char*)Pw + rb + (((l15 << 1) + 32) ^ sw)) = f2bf(p1);
        *(unsigned short*)((char*)Pw + rb + (((l15 << 1) + 64) ^ sw)) = f2bf(p2);
        *(unsigned short*)((char*)Pw + rb + (((l15 << 1) + 96) ^ sw)) = f2bf(p3);
      }

    // ---- PV: O[32 q][64 d] += P @ V  (same-wave P, compiler orders lgkmcnt)
    const char* Vl = (const char*)Vs[buf];
#pragma unroll
    for (int kt = 0; kt < 2; ++kt) {
      int q0r = l15, q1r = 16 + l15;
      bf16x8 pf0 = *(const bf16x8*)((const char*)Pw + (q0r << 7) +
                    (((kt << 6) + (lg << 4)) ^ ((q0r & 7) << 4)));
      bf16x8 pf1 = *(const bf16x8*)((const char*)Pw + (q1r << 7) +
                    (((kt << 6) + (lg << 4)) ^ ((q1r & 7) << 4)));
#pragma unroll
      for (int nf = 0; nf < 4; ++nf) {
        int d = l15 + nf * 16;
        bf16x8 vf = *(const bf16x8*)(Vl + (d << 7) +
                     (((kt << 6) + (lg << 4)) ^ ((d & 7) << 4)));
        oacc[0][nf] = __builtin_amdgcn_mfma_f32_16x16x32_bf16(pf0, vf, oacc[0][nf], 0, 0, 0);
        oacc[1][nf] = __builtin_amdgcn_mfma_f32_16x16x32_bf16(pf1, vf, oacc[1][nf], 0, 0, 0);
      }
    }

    // T14 write-late: commit next tile to the other LDS buffer
    if (tt < 31) {
      char* Kd = (char*)Ks[buf ^ 1];
      char* Vd = (char*)Vs[buf ^ 1];
      *(int4*)(Kd + sdst0) = kreg0;
      *(int4*)(Kd + sdst1) = kreg1;
      *(int4*)(Vd + sdst0) = vreg0;
      *(int4*)(Vd + sdst1) = vreg1;
    }
    __syncthreads();
  }

  // epilogue: normalize, store fp32 merged layout [(b*2048+tok)*1024 + h*64+d]
  float* Op = O + (size_t)(bh >> 4) * (2048u * 1024u) + (size_t)(bh & 15) * 64u;
#pragma unroll
  for (int mf = 0; mf < 2; ++mf)
#pragma unroll
    for (int r = 0; r < 4; ++r) {
      int ql = wq * 32 + mf * 16 + lg * 4 + r;
      float inv = 1.f / l_run[mf][r];
      float* row = Op + (size_t)(q0 + ql) * 1024u;
#pragma unroll
      for (int nf = 0; nf < 4; ++nf)
        row[l15 + nf * 16] = oacc[mf][nf][r] * inv;
    }
}

// ---------------------------------------------------------------------------
extern "C" void kernel_launch(void* const* d_in, const int* in_sizes, int n_in,
                              void* d_out, int out_size, void* d_ws, size_t ws_size,
                              hipStream_t stream) {
  (void)in_sizes; (void)n_in; (void)out_size; (void)ws_size;
  const float* hs = (const float*)d_in[0];
  const float* Wq = (const float*)d_in[1];
  const float* bq = (const float*)d_in[2];
  const float* Wk = (const float*)d_in[3];
  const float* bk = (const float*)d_in[4];
  const float* Wv = (const float*)d_in[5];
  const float* bv = (const float*)d_in[6];
  const float* Wo = (const float*)d_in[7];
  const float* bo = (const float*)d_in[8];
  float* out = (float*)d_out;

  // ws: tab[4096]f32 | Qbf 8MB | Kbf 8MB | Vt 8MB | Ab 16MB  (~40 MB)
  float* ws = (float*)d_ws;
  float* tab = ws;
  unsigned short* Qbf = (unsigned short*)(ws + 4096);
  unsigned short* Kbf = Qbf + 4194304u;
  unsigned short* Vtg = Kbf + 4194304u;
  float* Ab = (float*)(Vtg + 4194304u);

  tor_table_k<<<16, 256, 0, stream>>>(tab);

  dim3 gg(8, 32);  // N/128 x M/128
  gemm_bias_k<1><<<gg, 256, 0, stream>>>(hs, Wq, bq, nullptr, Qbf);
  gemm_bias_k<1><<<gg, 256, 0, stream>>>(hs, Wk, bk, nullptr, Kbf);
  gemm_bias_k<2><<<gg, 256, 0, stream>>>(hs, Wv, bv, nullptr, Vtg);

  attn_mfma_k<<<dim3(16, 32), 256, 0, stream>>>(Qbf, Kbf, Vtg, tab, Ab);

  gemm_bias_k<0><<<gg, 256, 0, stream>>>(Ab, Wo, bo, out, nullptr);
}

// Round 9
// 356.363 us; speedup vs baseline: 3.2950x; 2.1111x over previous
//
#include <hip/hip_runtime.h>
#include <math.h>

// ---------------------------------------------------------------------------
// HodgeTorsionAttention R7: all-MFMA pipeline.
//   casts -> 3x bf16 MFMA GEMM (QKV) -> bf16 MFMA flash attn (hi/lo out)
//   -> 3-pass split-bf16 MFMA out-projection (near-fp32 quality).
// B=2, S=2048, D=1024, H=16, hd=64.
// ---------------------------------------------------------------------------

typedef __attribute__((ext_vector_type(8))) short bf16x8;   // 8 bf16 = 4 VGPR
typedef __attribute__((ext_vector_type(4))) float f32x4;    // MFMA acc

__device__ __forceinline__ unsigned short f2bf(float f) {   // RNE f32->bf16
  unsigned u = __float_as_uint(f);
  return (unsigned short)((u + 0x7FFFu + ((u >> 16) & 1u)) >> 16);
}
__device__ __forceinline__ float bf2f(unsigned short h) {
  return __uint_as_float(((unsigned)h) << 16);
}
__device__ __forceinline__ int pack2(unsigned short a, unsigned short b) {
  return (int)(((unsigned)b << 16) | (unsigned)a);
}

// ---------------- torsion table: tab[i] = phi*sin(giza*(i-2047)), i<4096 ----
__global__ __launch_bounds__(256) void tor_table_k(float* __restrict__ tab) {
  int i = blockIdx.x * 256 + threadIdx.x;
  if (i < 4096) {
    double delta = (double)(i - 2047);
    double giza = 51.85 * M_PI / 180.0;
    tab[i] = (float)(1.618033988749895 * sin(giza * delta));
  }
}

// ---------------- cast hs [4096][1024] f32 -> bf16 row-major ----------------
__global__ __launch_bounds__(256) void cast_hs_k(const float* __restrict__ X,
                                                 unsigned short* __restrict__ Y) {
  int i = (blockIdx.x * 256 + threadIdx.x) * 8;
  float4 a = *(const float4*)&X[i];
  float4 b = *(const float4*)&X[i + 4];
  int4 o;
  o.x = pack2(f2bf(a.x), f2bf(a.y));
  o.y = pack2(f2bf(a.z), f2bf(a.w));
  o.z = pack2(f2bf(b.x), f2bf(b.y));
  o.w = pack2(f2bf(b.z), f2bf(b.w));
  *(int4*)&Y[i] = o;
}

// ---------------- transpose-cast W [1024 k][1024 n] -> Wt [n][k] bf16 -------
// SPLIT: also emit lo = bf16(v - hi) for the compensated out-projection.
template <bool SPLIT>
__global__ __launch_bounds__(256) void cast_wt_k(const float* __restrict__ W,
                                                 unsigned short* __restrict__ Th,
                                                 unsigned short* __restrict__ Tl) {
  const int lane = threadIdx.x & 63, w = threadIdx.x >> 6;
  const int n = blockIdx.x * 64 + lane;
  const int k0 = blockIdx.y * 32 + w * 8;
  float v[8];
#pragma unroll
  for (int j = 0; j < 8; ++j) v[j] = W[(size_t)(k0 + j) * 1024u + n];  // coalesced
  unsigned short h[8];
#pragma unroll
  for (int j = 0; j < 8; ++j) h[j] = f2bf(v[j]);
  int4 hp;
  hp.x = pack2(h[0], h[1]); hp.y = pack2(h[2], h[3]);
  hp.z = pack2(h[4], h[5]); hp.w = pack2(h[6], h[7]);
  *(int4*)&Th[(size_t)n * 1024u + k0] = hp;
  if (SPLIT) {
    unsigned short lo[8];
#pragma unroll
    for (int j = 0; j < 8; ++j) lo[j] = f2bf(v[j] - bf2f(h[j]));
    int4 lp;
    lp.x = pack2(lo[0], lo[1]); lp.y = pack2(lo[2], lo[3]);
    lp.z = pack2(lo[4], lo[5]); lp.w = pack2(lo[6], lo[7]);
    *(int4*)&Tl[(size_t)n * 1024u + k0] = lp;
  }
}

// ---------------- bf16 MFMA GEMM: C[4096,1024] = A @ Bt^T + bias ------------
// A [4096 m][1024 k] bf16 row-major; Bt [1024 n][1024 k] bf16 (W transposed).
// 128x128 tile, BK=64, 256 thr = 4 waves (2x2), per-wave 64x64, dbuf LDS
// with attn-validated ((row&7)<<4) XOR swizzle on 128B rows, T14 staging.
// OMODE 0: fp32 merged [m][1024]; ACC: C += (no bias).
// OMODE 1: bf16 head-split [bh][tok][64]   (Q, K)
// OMODE 2: bf16 head-split V-transposed [bh][64][2048]
template <int OMODE, bool ACC>
__global__ __launch_bounds__(256) void gemm_mfma_k(
    const unsigned short* __restrict__ A, const unsigned short* __restrict__ Bt,
    const float* __restrict__ bias, float* __restrict__ C,
    unsigned short* __restrict__ Cb)
{
  __shared__ unsigned short Asw[2][8192];  // [128 m][64 k] swizzled, 16KB ea
  __shared__ unsigned short Bsw[2][8192];  // [128 n][64 k] swizzled

  const int t = threadIdx.x;
  const int l = t & 63, wq = t >> 6;
  const int l15 = l & 15, lg = l >> 4;
  const int wm = wq >> 1, wn = wq & 1;
  const int m0 = blockIdx.y << 7, n0 = blockIdx.x << 7;

  // staging: thread -> (row = it*32 + t>>3, 16B chunk (t&7)*16); rows coalesce
  const int srow = t >> 3;
  const int scb = (t & 7) << 4;
  const int swz = (srow & 7) << 4;
  int dst[4];
#pragma unroll
  for (int it = 0; it < 4; ++it)
    dst[it] = (it * 32 + srow) * 128 + (scb ^ swz);
  const char* Ap = (const char*)A + (size_t)(m0 + srow) * 2048u + (size_t)scb;
  const char* Bp = (const char*)Bt + (size_t)(n0 + srow) * 2048u + (size_t)scb;

  f32x4 acc[4][4];
#pragma unroll
  for (int mf = 0; mf < 4; ++mf)
#pragma unroll
    for (int nf = 0; nf < 4; ++nf) {
      f32x4 z = {0.f, 0.f, 0.f, 0.f};
      acc[mf][nf] = z;
    }

  int4 ra[4], rb[4];
#pragma unroll
  for (int it = 0; it < 4; ++it) {
    ra[it] = *(const int4*)(Ap + (size_t)it * 65536u);
    rb[it] = *(const int4*)(Bp + (size_t)it * 65536u);
  }
#pragma unroll
  for (int it = 0; it < 4; ++it) {
    *(int4*)((char*)Asw[0] + dst[it]) = ra[it];
    *(int4*)((char*)Bsw[0] + dst[it]) = rb[it];
  }
  __syncthreads();

  const int fswz = (l15 & 7) << 4;

  for (int tt = 0; tt < 16; ++tt) {
    const int buf = tt & 1;
    if (tt < 15) {                       // T14 issue-early next K-slice
      const size_t ko = (size_t)(tt + 1) * 128u;  // 64 elems * 2B
#pragma unroll
      for (int it = 0; it < 4; ++it) {
        ra[it] = *(const int4*)(Ap + (size_t)it * 65536u + ko);
        rb[it] = *(const int4*)(Bp + (size_t)it * 65536u + ko);
      }
    }
    const char* Al = (const char*)Asw[buf];
    const char* Bl = (const char*)Bsw[buf];
#pragma unroll
    for (int kt = 0; kt < 2; ++kt) {
      bf16x8 af[4], bfr[4];
#pragma unroll
      for (int mf = 0; mf < 4; ++mf) {
        int r = wm * 64 + mf * 16 + l15;
        af[mf] = *(const bf16x8*)(Al + r * 128 + ((kt * 64 + lg * 16) ^ fswz));
      }
#pragma unroll
      for (int nf = 0; nf < 4; ++nf) {
        int r = wn * 64 + nf * 16 + l15;
        bfr[nf] = *(const bf16x8*)(Bl + r * 128 + ((kt * 64 + lg * 16) ^ fswz));
      }
#pragma unroll
      for (int mf = 0; mf < 4; ++mf)
#pragma unroll
        for (int nf = 0; nf < 4; ++nf)
          acc[mf][nf] = __builtin_amdgcn_mfma_f32_16x16x32_bf16(af[mf], bfr[nf],
                                                                acc[mf][nf], 0, 0, 0);
    }
    if (tt < 15) {                       // T14 write-late into other buffer
      char* Ad = (char*)Asw[buf ^ 1];
      char* Bd = (char*)Bsw[buf ^ 1];
#pragma unroll
      for (int it = 0; it < 4; ++it) {
        *(int4*)(Ad + dst[it]) = ra[it];
        *(int4*)(Bd + dst[it]) = rb[it];
      }
    }
    __syncthreads();
  }

  // epilogue: C/D layout col=l15, row=lg*4+reg (m89)
#pragma unroll
  for (int mf = 0; mf < 4; ++mf)
#pragma unroll
    for (int r = 0; r < 4; ++r) {
      const int m = m0 + wm * 64 + mf * 16 + lg * 4 + r;
#pragma unroll
      for (int nf = 0; nf < 4; ++nf) {
        const int n = n0 + wn * 64 + nf * 16 + l15;
        float v = acc[mf][nf][r];
        if (OMODE == 0) {
          size_t idx = (size_t)m * 1024u + n;
          v += ACC ? C[idx] : bias[n];
          C[idx] = v;
        } else {
          v += bias[n];
          int bsel = m >> 11, tok = m & 2047;
          int h = n >> 6, d = n & 63;
          if (OMODE == 1)
            Cb[(size_t)((bsel << 4) + h) * 131072u + (size_t)tok * 64u + d] = f2bf(v);
          else
            Cb[(size_t)((bsel << 4) + h) * 131072u + (size_t)d * 2048u + tok] = f2bf(v);
        }
      }
    }
}

// ---------------- bf16 MFMA flash attention (validated R2 core) -------------
// Epilogue now writes hi/lo bf16 split of the output for the out-projection.
__global__ __launch_bounds__(256) void attn_mfma_k(
    const unsigned short* __restrict__ Qb, const unsigned short* __restrict__ Kb,
    const unsigned short* __restrict__ Vtg, const float* __restrict__ tab,
    unsigned short* __restrict__ Ahi, unsigned short* __restrict__ Alo)
{
  __shared__ unsigned short Ks[2][4096];
  __shared__ unsigned short Vs[2][4096];
  __shared__ unsigned short Ps[4][2048];
  __shared__ float tors[2176];

  const int t  = threadIdx.x;
  const int l  = t & 63;
  const int wq = t >> 6;
  const int l15 = l & 15, lg = l >> 4;
  const int q0 = blockIdx.x << 7;
  const int bh = blockIdx.y;

  for (int x = t; x < 2176; x += 256) tors[x] = tab[1920 - q0 + x];

  const unsigned short* Qp = Qb + (size_t)bh * 131072u;
  const char* Kpanel = (const char*)(Kb  + (size_t)bh * 131072u);
  const char* Vpanel = (const char*)(Vtg + (size_t)bh * 131072u);

  bf16x8 qf[2][2];
#pragma unroll
  for (int mf = 0; mf < 2; ++mf)
#pragma unroll
    for (int kt = 0; kt < 2; ++kt) {
      int tok = q0 + wq * 32 + mf * 16 + l15;
      qf[mf][kt] = *(const bf16x8*)&Qp[(size_t)tok * 64u + (size_t)(kt * 32 + lg * 8)];
    }

  f32x4 oacc[2][4];
  float m_run[2][4], l_run[2][4];
#pragma unroll
  for (int mf = 0; mf < 2; ++mf)
#pragma unroll
    for (int r = 0; r < 4; ++r) {
      m_run[mf][r] = -1e30f; l_run[mf][r] = 0.f;
      f32x4 z = {0.f, 0.f, 0.f, 0.f};
      oacc[mf][r] = z;
    }

  const int sb    = (wq * 2) * 1024 + l * 16;
  const int srow0 = sb >> 7,          scol0 = sb & 127;
  const int srow1 = (sb + 1024) >> 7, scol1 = (sb + 1024) & 127;
  const int sdst0 = srow0 * 128 + (scol0 ^ ((srow0 & 7) << 4));
  const int sdst1 = srow1 * 128 + (scol1 ^ ((srow1 & 7) << 4));

  int4 kreg0, kreg1, vreg0, vreg1;
  kreg0 = *(const int4*)(Kpanel + sb);
  kreg1 = *(const int4*)(Kpanel + sb + 1024);
  vreg0 = *(const int4*)(Vpanel + (size_t)srow0 * 4096u + (size_t)scol0);
  vreg1 = *(const int4*)(Vpanel + (size_t)srow1 * 4096u + (size_t)scol1);
  *(int4*)((char*)Ks[0] + sdst0) = kreg0;
  *(int4*)((char*)Ks[0] + sdst1) = kreg1;
  *(int4*)((char*)Vs[0] + sdst0) = vreg0;
  *(int4*)((char*)Vs[0] + sdst1) = vreg1;
  __syncthreads();

  unsigned short* Pw = Ps[wq];

  for (int tt = 0; tt < 32; ++tt) {
    const int buf = tt & 1;
    const int kc  = tt << 6;

    if (tt < 31) {
      const char* kp = Kpanel + (tt + 1) * 8192;
      kreg0 = *(const int4*)(kp + sb);
      kreg1 = *(const int4*)(kp + sb + 1024);
      const char* vp = Vpanel + (tt + 1) * 128;
      vreg0 = *(const int4*)(vp + (size_t)srow0 * 4096u + (size_t)scol0);
      vreg1 = *(const int4*)(vp + (size_t)srow1 * 4096u + (size_t)scol1);
    }

    f32x4 sacc[2][4];
#pragma unroll
    for (int mf = 0; mf < 2; ++mf)
#pragma unroll
      for (int nf = 0; nf < 4; ++nf) {
        f32x4 z = {0.f, 0.f, 0.f, 0.f};
        sacc[mf][nf] = z;
      }
    const char* Kl = (const char*)Ks[buf];
#pragma unroll
    for (int kt = 0; kt < 2; ++kt) {
#pragma unroll
      for (int nf = 0; nf < 4; ++nf) {
        int key = l15 + nf * 16;
        bf16x8 kf = *(const bf16x8*)(Kl + (key << 7) +
                     (((kt << 6) + (lg << 4)) ^ ((key & 7) << 4)));
        sacc[0][nf] = __builtin_amdgcn_mfma_f32_16x16x32_bf16(qf[0][kt], kf, sacc[0][nf], 0, 0, 0);
        sacc[1][nf] = __builtin_amdgcn_mfma_f32_16x16x32_bf16(qf[1][kt], kf, sacc[1][nf], 0, 0, 0);
      }
    }

#pragma unroll
    for (int mf = 0; mf < 2; ++mf)
#pragma unroll
      for (int r = 0; r < 4; ++r) {
        int ql = wq * 32 + mf * 16 + lg * 4 + r;
        int tb = 127 + kc + l15 - ql;
        float x0 = fmaf(sacc[mf][0][r], 0.125f, tors[tb]);
        float x1 = fmaf(sacc[mf][1][r], 0.125f, tors[tb + 16]);
        float x2 = fmaf(sacc[mf][2][r], 0.125f, tors[tb + 32]);
        float x3 = fmaf(sacc[mf][3][r], 0.125f, tors[tb + 48]);
        float mx = fmaxf(fmaxf(x0, x1), fmaxf(x2, x3));
        mx = fmaxf(mx, __shfl_xor(mx, 1, 64));
        mx = fmaxf(mx, __shfl_xor(mx, 2, 64));
        mx = fmaxf(mx, __shfl_xor(mx, 4, 64));
        mx = fmaxf(mx, __shfl_xor(mx, 8, 64));
        float mold = m_run[mf][r];
        float mnew = fmaxf(mold, mx);
        float alpha = __expf(mold - mnew);
        float p0 = __expf(x0 - mnew);
        float p1 = __expf(x1 - mnew);
        float p2 = __expf(x2 - mnew);
        float p3 = __expf(x3 - mnew);
        float ls = (p0 + p1) + (p2 + p3);
        ls += __shfl_xor(ls, 1, 64);
        ls += __shfl_xor(ls, 2, 64);
        ls += __shfl_xor(ls, 4, 64);
        ls += __shfl_xor(ls, 8, 64);
        m_run[mf][r] = mnew;
        l_run[mf][r] = l_run[mf][r] * alpha + ls;
        oacc[mf][0][r] *= alpha;
        oacc[mf][1][r] *= alpha;
        oacc[mf][2][r] *= alpha;
        oacc[mf][3][r] *= alpha;
        int qrow = mf * 16 + lg * 4 + r;
        int rb = qrow << 7, sw = (qrow & 7) << 4;
        *(unsigned short*)((char*)Pw + rb + (((l15 << 1) +  0) ^ sw)) = f2bf(p0);
        *(unsigned short*)((char*)Pw + rb + (((l15 << 1) + 32) ^ sw)) = f2bf(p1);
        *(unsigned short*)((char*)Pw + rb + (((l15 << 1) + 64) ^ sw)) = f2bf(p2);
        *(unsigned short*)((char*)Pw + rb + (((l15 << 1) + 96) ^ sw)) = f2bf(p3);
      }

    const char* Vl = (const char*)Vs[buf];
#pragma unroll
    for (int kt = 0; kt < 2; ++kt) {
      int q0r = l15, q1r = 16 + l15;
      bf16x8 pf0 = *(const bf16x8*)((const char*)Pw + (q0r << 7) +
                    (((kt << 6) + (lg << 4)) ^ ((q0r & 7) << 4)));
      bf16x8 pf1 = *(const bf16x8*)((const char*)Pw + (q1r << 7) +
                    (((kt << 6) + (lg << 4)) ^ ((q1r & 7) << 4)));
#pragma unroll
      for (int nf = 0; nf < 4; ++nf) {
        int d = l15 + nf * 16;
        bf16x8 vf = *(const bf16x8*)(Vl + (d << 7) +
                     (((kt << 6) + (lg << 4)) ^ ((d & 7) << 4)));
        oacc[0][nf] = __builtin_amdgcn_mfma_f32_16x16x32_bf16(pf0, vf, oacc[0][nf], 0, 0, 0);
        oacc[1][nf] = __builtin_amdgcn_mfma_f32_16x16x32_bf16(pf1, vf, oacc[1][nf], 0, 0, 0);
      }
    }

    if (tt < 31) {
      char* Kd = (char*)Ks[buf ^ 1];
      char* Vd = (char*)Vs[buf ^ 1];
      *(int4*)(Kd + sdst0) = kreg0;
      *(int4*)(Kd + sdst1) = kreg1;
      *(int4*)(Vd + sdst0) = vreg0;
      *(int4*)(Vd + sdst1) = vreg1;
    }
    __syncthreads();
  }

  // epilogue: normalize + hi/lo bf16 split, merged layout [(b*S+tok)*1024+h*64+d]
  size_t ebase = (size_t)(bh >> 4) * (2048u * 1024u) + (size_t)(bh & 15) * 64u;
#pragma unroll
  for (int mf = 0; mf < 2; ++mf)
#pragma unroll
    for (int r = 0; r < 4; ++r) {
      int ql = wq * 32 + mf * 16 + lg * 4 + r;
      float inv = 1.f / l_run[mf][r];
      size_t roff = ebase + (size_t)(q0 + ql) * 1024u;
#pragma unroll
      for (int nf = 0; nf < 4; ++nf) {
        float v = oacc[mf][nf][r] * inv;
        unsigned short h = f2bf(v);
        Ahi[roff + l15 + nf * 16] = h;
        Alo[roff + l15 + nf * 16] = f2bf(v - bf2f(h));
      }
    }
}

// ---------------------------------------------------------------------------
extern "C" void kernel_launch(void* const* d_in, const int* in_sizes, int n_in,
                              void* d_out, int out_size, void* d_ws, size_t ws_size,
                              hipStream_t stream) {
  (void)in_sizes; (void)n_in; (void)out_size; (void)ws_size;
  const float* hs = (const float*)d_in[0];
  const float* Wq = (const float*)d_in[1];
  const float* bq = (const float*)d_in[2];
  const float* Wk = (const float*)d_in[3];
  const float* bk = (const float*)d_in[4];
  const float* Wv = (const float*)d_in[5];
  const float* bv = (const float*)d_in[6];
  const float* Wo = (const float*)d_in[7];
  const float* bo = (const float*)d_in[8];
  float* out = (float*)d_out;

  // ws: tab | hs_bf 8MB | Wqt,Wkt,Wvt,Woh,Wol 2MB ea | Qbf,Kbf,Vtg 8MB ea
  //     | Ahi,Alo 8MB ea   (~58 MB)
  float* ws = (float*)d_ws;
  float* tab = ws;
  unsigned short* hs_bf = (unsigned short*)(ws + 4096);
  unsigned short* Wqt = hs_bf + 4194304u;
  unsigned short* Wkt = Wqt + 1048576u;
  unsigned short* Wvt = Wkt + 1048576u;
  unsigned short* Woh = Wvt + 1048576u;
  unsigned short* Wol = Woh + 1048576u;
  unsigned short* Qbf = Wol + 1048576u;
  unsigned short* Kbf = Qbf + 4194304u;
  unsigned short* Vtg = Kbf + 4194304u;
  unsigned short* Ahi = Vtg + 4194304u;
  unsigned short* Alo = Ahi + 4194304u;

  tor_table_k<<<16, 256, 0, stream>>>(tab);
  cast_hs_k<<<2048, 256, 0, stream>>>(hs, hs_bf);
  dim3 gc(16, 32);
  cast_wt_k<false><<<gc, 256, 0, stream>>>(Wq, Wqt, nullptr);
  cast_wt_k<false><<<gc, 256, 0, stream>>>(Wk, Wkt, nullptr);
  cast_wt_k<false><<<gc, 256, 0, stream>>>(Wv, Wvt, nullptr);
  cast_wt_k<true ><<<gc, 256, 0, stream>>>(Wo, Woh, Wol);

  dim3 gg(8, 32);  // N/128 x M/128
  gemm_mfma_k<1, false><<<gg, 256, 0, stream>>>(hs_bf, Wqt, bq, nullptr, Qbf);
  gemm_mfma_k<1, false><<<gg, 256, 0, stream>>>(hs_bf, Wkt, bk, nullptr, Kbf);
  gemm_mfma_k<2, false><<<gg, 256, 0, stream>>>(hs_bf, Wvt, bv, nullptr, Vtg);

  attn_mfma_k<<<dim3(16, 32), 256, 0, stream>>>(Qbf, Kbf, Vtg, tab, Ahi, Alo);

  // out-proj: C = Ahi*Woh + bo, += Alo*Woh, += Ahi*Wol  (split-bf16, ~fp32)
  gemm_mfma_k<0, false><<<gg, 256, 0, stream>>>(Ahi, Woh, bo, out, nullptr);
  gemm_mfma_k<0, true ><<<gg, 256, 0, stream>>>(Alo, Woh, bo, out, nullptr);
  gemm_mfma_k<0, true ><<<gg, 256, 0, stream>>>(Ahi, Wol, bo, out, nullptr);
}

// Round 11
// 330.096 us; speedup vs baseline: 3.5572x; 1.0796x over previous
//
#include <hip/hip_runtime.h>
#include <math.h>

// ---------------------------------------------------------------------------
// HodgeTorsionAttention R10:
//   casts -> fused QKV bf16 MFMA GEMM (N=3072) -> bf16 MFMA flash attn with
//   fixed-shift exp2 softmax (no max/rescale) -> fused 3-product split-bf16
//   out-projection. B=2, S=2048, D=1024, H=16, hd=64.
// ---------------------------------------------------------------------------

typedef __attribute__((ext_vector_type(8))) short bf16x8;   // 8 bf16 = 4 VGPR
typedef __attribute__((ext_vector_type(4))) float f32x4;    // MFMA acc

__device__ __forceinline__ unsigned short f2bf(float f) {   // RNE f32->bf16
  unsigned u = __float_as_uint(f);
  return (unsigned short)((u + 0x7FFFu + ((u >> 16) & 1u)) >> 16);
}
__device__ __forceinline__ float bf2f(unsigned short h) {
  return __uint_as_float(((unsigned)h) << 16);
}
__device__ __forceinline__ int pack2(unsigned short a, unsigned short b) {
  return (int)(((unsigned)b << 16) | (unsigned)a);
}

// C1 = 0.125 * log2(e): folds the 1/sqrt(hd) scale and the exp->exp2 change.
#define C1_SCALE 0.18033688011112042f

// -------- torsion table (pre-folded): tab[i] = tor(i-2047)*log2e - 8*log2e --
// softmax: p = exp2(qk*C1 + tab[...]) == exp(qk/8 + tor - 8); shift 8 is safe
// (scores bounded ~4; softmax shift-invariant; fp32 l-sum cannot overflow).
__global__ __launch_bounds__(256) void tor_table_k(float* __restrict__ tab) {
  int i = blockIdx.x * 256 + threadIdx.x;
  if (i < 4096) {
    double delta = (double)(i - 2047);
    double giza = 51.85 * M_PI / 180.0;
    double l2e = 1.4426950408889634;
    tab[i] = (float)((1.618033988749895 * sin(giza * delta)) * l2e - 8.0 * l2e);
  }
}

// ---------------- cast hs [4096][1024] f32 -> bf16 row-major ----------------
__global__ __launch_bounds__(256) void cast_hs_k(const float* __restrict__ X,
                                                 unsigned short* __restrict__ Y) {
  int i = (blockIdx.x * 256 + threadIdx.x) * 8;
  float4 a = *(const float4*)&X[i];
  float4 b = *(const float4*)&X[i + 4];
  int4 o;
  o.x = pack2(f2bf(a.x), f2bf(a.y));
  o.y = pack2(f2bf(a.z), f2bf(a.w));
  o.z = pack2(f2bf(b.x), f2bf(b.y));
  o.w = pack2(f2bf(b.z), f2bf(b.w));
  *(int4*)&Y[i] = o;
}

// ---------------- transpose-cast W [1024 k][1024 n] -> Wt [n][k] bf16 -------
template <bool SPLIT>
__global__ __launch_bounds__(256) void cast_wt_k(const float* __restrict__ W,
                                                 unsigned short* __restrict__ Th,
                                                 unsigned short* __restrict__ Tl) {
  const int lane = threadIdx.x & 63, w = threadIdx.x >> 6;
  const int n = blockIdx.x * 64 + lane;
  const int k0 = blockIdx.y * 32 + w * 8;
  float v[8];
#pragma unroll
  for (int j = 0; j < 8; ++j) v[j] = W[(size_t)(k0 + j) * 1024u + n];
  unsigned short h[8];
#pragma unroll
  for (int j = 0; j < 8; ++j) h[j] = f2bf(v[j]);
  int4 hp;
  hp.x = pack2(h[0], h[1]); hp.y = pack2(h[2], h[3]);
  hp.z = pack2(h[4], h[5]); hp.w = pack2(h[6], h[7]);
  *(int4*)&Th[(size_t)n * 1024u + k0] = hp;
  if (SPLIT) {
    unsigned short lo[8];
#pragma unroll
    for (int j = 0; j < 8; ++j) lo[j] = f2bf(v[j] - bf2f(h[j]));
    int4 lp;
    lp.x = pack2(lo[0], lo[1]); lp.y = pack2(lo[2], lo[3]);
    lp.z = pack2(lo[4], lo[5]); lp.w = pack2(lo[6], lo[7]);
    *(int4*)&Tl[(size_t)n * 1024u + k0] = lp;
  }
}

// ---------------- fused QKV bf16 MFMA GEMM ----------------------------------
// One launch, grid (24, 32): blockIdx.x third = Q/K/V. Wt3 = [3072 n][1024 k].
// Q,K -> head-split [bh][tok][64] (QK base, K at +4194304).
// V   -> transposed [bh][64][2048] with paired-key column permutation:
//        within each 32-tok group, pos = (k<16) ? 2k : 2(k-16)+1  (so attn's
//        P pairs (key, key+16) pack into one b32 LDS write; PV order-invariant).
__global__ __launch_bounds__(256) void gemm_qkv_k(
    const unsigned short* __restrict__ A, const unsigned short* __restrict__ Wt3,
    const float* __restrict__ bq, const float* __restrict__ bk,
    const float* __restrict__ bv,
    unsigned short* __restrict__ QK, unsigned short* __restrict__ Vt)
{
  __shared__ unsigned short Asw[2][8192];  // [128 m][64 k] swizzled
  __shared__ unsigned short Bsw[2][8192];  // [128 n][64 k] swizzled

  const int t = threadIdx.x;
  const int l = t & 63, wq = t >> 6;
  const int l15 = l & 15, lg = l >> 4;
  const int wm = wq >> 1, wn = wq & 1;
  const int third = blockIdx.x >> 3;
  const int n0 = (blockIdx.x & 7) << 7;   // local n within the third
  const int m0 = blockIdx.y << 7;

  const int srow = t >> 3;
  const int scb = (t & 7) << 4;
  const int swz = (srow & 7) << 4;
  int dst[4];
#pragma unroll
  for (int it = 0; it < 4; ++it)
    dst[it] = (it * 32 + srow) * 128 + (scb ^ swz);
  const char* Ap = (const char*)A + (size_t)(m0 + srow) * 2048u + (size_t)scb;
  const char* Bp = (const char*)Wt3 + (size_t)third * 2097152u +
                   (size_t)(n0 + srow) * 2048u + (size_t)scb;

  f32x4 acc[4][4];
#pragma unroll
  for (int mf = 0; mf < 4; ++mf)
#pragma unroll
    for (int nf = 0; nf < 4; ++nf) {
      f32x4 z = {0.f, 0.f, 0.f, 0.f};
      acc[mf][nf] = z;
    }

  int4 ra[4], rb[4];
#pragma unroll
  for (int it = 0; it < 4; ++it) {
    ra[it] = *(const int4*)(Ap + (size_t)it * 65536u);
    rb[it] = *(const int4*)(Bp + (size_t)it * 65536u);
  }
#pragma unroll
  for (int it = 0; it < 4; ++it) {
    *(int4*)((char*)Asw[0] + dst[it]) = ra[it];
    *(int4*)((char*)Bsw[0] + dst[it]) = rb[it];
  }
  __syncthreads();

  const int fswz = (l15 & 7) << 4;

  for (int tt = 0; tt < 16; ++tt) {
    const int buf = tt & 1;
    if (tt < 15) {
      const size_t ko = (size_t)(tt + 1) * 128u;
#pragma unroll
      for (int it = 0; it < 4; ++it) {
        ra[it] = *(const int4*)(Ap + (size_t)it * 65536u + ko);
        rb[it] = *(const int4*)(Bp + (size_t)it * 65536u + ko);
      }
    }
    const char* Al = (const char*)Asw[buf];
    const char* Bl = (const char*)Bsw[buf];
#pragma unroll
    for (int kt = 0; kt < 2; ++kt) {
      bf16x8 af[4], bfr[4];
#pragma unroll
      for (int mf = 0; mf < 4; ++mf) {
        int r = wm * 64 + mf * 16 + l15;
        af[mf] = *(const bf16x8*)(Al + r * 128 + ((kt * 64 + lg * 16) ^ fswz));
      }
#pragma unroll
      for (int nf = 0; nf < 4; ++nf) {
        int r = wn * 64 + nf * 16 + l15;
        bfr[nf] = *(const bf16x8*)(Bl + r * 128 + ((kt * 64 + lg * 16) ^ fswz));
      }
#pragma unroll
      for (int mf = 0; mf < 4; ++mf)
#pragma unroll
        for (int nf = 0; nf < 4; ++nf)
          acc[mf][nf] = __builtin_amdgcn_mfma_f32_16x16x32_bf16(af[mf], bfr[nf],
                                                                acc[mf][nf], 0, 0, 0);
    }
    if (tt < 15) {
      char* Ad = (char*)Asw[buf ^ 1];
      char* Bd = (char*)Bsw[buf ^ 1];
#pragma unroll
      for (int it = 0; it < 4; ++it) {
        *(int4*)(Ad + dst[it]) = ra[it];
        *(int4*)(Bd + dst[it]) = rb[it];
      }
    }
    __syncthreads();
  }

  const float* bs = (third == 0) ? bq : (third == 1) ? bk : bv;
  unsigned short* QKb = QK + (size_t)third * 4194304u;   // valid for third<2
#pragma unroll
  for (int mf = 0; mf < 4; ++mf)
#pragma unroll
    for (int r = 0; r < 4; ++r) {
      const int m = m0 + wm * 64 + mf * 16 + lg * 4 + r;
      const int bsel = m >> 11, tok = m & 2047;
#pragma unroll
      for (int nf = 0; nf < 4; ++nf) {
        const int nl = n0 + wn * 64 + nf * 16 + l15;
        float v = acc[mf][nf][r] + bs[nl];
        const int h = nl >> 6, d = nl & 63;
        if (third < 2) {
          QKb[(size_t)((bsel << 4) + h) * 131072u + (size_t)tok * 64u + d] = f2bf(v);
        } else {
          int lk = tok & 31;
          int pos = (lk < 16) ? (lk << 1) : (((lk - 16) << 1) | 1);
          int tokp = (tok & ~31) | pos;
          Vt[(size_t)((bsel << 4) + h) * 131072u + (size_t)d * 2048u + tokp] = f2bf(v);
        }
      }
    }
}

// ---------------- bf16 MFMA flash attention (fixed-shift softmax) -----------
__global__ __launch_bounds__(256) void attn_mfma_k(
    const unsigned short* __restrict__ Qb, const unsigned short* __restrict__ Kb,
    const unsigned short* __restrict__ Vtg, const float* __restrict__ tab,
    unsigned short* __restrict__ Ahi, unsigned short* __restrict__ Alo)
{
  __shared__ unsigned short Ks[2][4096];  // [64 key][64 dim] swizzled
  __shared__ unsigned short Vs[2][4096];  // [64 dim][64 key-pos] swizzled
  __shared__ unsigned short Ps[4][2048];  // per-wave [32 q][64 key-pos] swizzled
  __shared__ float tors[2176];            // pre-folded: tor*log2e - 8*log2e

  const int t  = threadIdx.x;
  const int l  = t & 63;
  const int wq = t >> 6;
  const int l15 = l & 15, lg = l >> 4;
  const int q0 = blockIdx.x << 7;
  const int bh = blockIdx.y;

  for (int x = t; x < 2176; x += 256) tors[x] = tab[1920 - q0 + x];

  const unsigned short* Qp = Qb + (size_t)bh * 131072u;
  const char* Kpanel = (const char*)(Kb  + (size_t)bh * 131072u);
  const char* Vpanel = (const char*)(Vtg + (size_t)bh * 131072u);

  bf16x8 qf[2][2];
#pragma unroll
  for (int mf = 0; mf < 2; ++mf)
#pragma unroll
    for (int kt = 0; kt < 2; ++kt) {
      int tok = q0 + wq * 32 + mf * 16 + l15;
      qf[mf][kt] = *(const bf16x8*)&Qp[(size_t)tok * 64u + (size_t)(kt * 32 + lg * 8)];
    }

  f32x4 oacc[2][4];
  float l_part[2][4];
#pragma unroll
  for (int mf = 0; mf < 2; ++mf)
#pragma unroll
    for (int r = 0; r < 4; ++r) {
      l_part[mf][r] = 0.f;
      f32x4 z = {0.f, 0.f, 0.f, 0.f};
      oacc[mf][r] = z;
    }

  const int sb    = (wq * 2) * 1024 + l * 16;
  const int srow0 = sb >> 7,          scol0 = sb & 127;
  const int srow1 = (sb + 1024) >> 7, scol1 = (sb + 1024) & 127;
  const int sdst0 = srow0 * 128 + (scol0 ^ ((srow0 & 7) << 4));
  const int sdst1 = srow1 * 128 + (scol1 ^ ((srow1 & 7) << 4));

  int4 kreg0, kreg1, vreg0, vreg1;
  kreg0 = *(const int4*)(Kpanel + sb);
  kreg1 = *(const int4*)(Kpanel + sb + 1024);
  vreg0 = *(const int4*)(Vpanel + (size_t)srow0 * 4096u + (size_t)scol0);
  vreg1 = *(const int4*)(Vpanel + (size_t)srow1 * 4096u + (size_t)scol1);
  *(int4*)((char*)Ks[0] + sdst0) = kreg0;
  *(int4*)((char*)Ks[0] + sdst1) = kreg1;
  *(int4*)((char*)Vs[0] + sdst0) = vreg0;
  *(int4*)((char*)Vs[0] + sdst1) = vreg1;
  __syncthreads();

  unsigned short* Pw = Ps[wq];

  for (int tt = 0; tt < 32; ++tt) {
    const int buf = tt & 1;
    const int kc  = tt << 6;

    if (tt < 31) {   // T14 issue-early
      const char* kp = Kpanel + (tt + 1) * 8192;
      kreg0 = *(const int4*)(kp + sb);
      kreg1 = *(const int4*)(kp + sb + 1024);
      const char* vp = Vpanel + (tt + 1) * 128;
      vreg0 = *(const int4*)(vp + (size_t)srow0 * 4096u + (size_t)scol0);
      vreg1 = *(const int4*)(vp + (size_t)srow1 * 4096u + (size_t)scol1);
    }

    // ---- QK^T
    f32x4 sacc[2][4];
#pragma unroll
    for (int mf = 0; mf < 2; ++mf)
#pragma unroll
      for (int nf = 0; nf < 4; ++nf) {
        f32x4 z = {0.f, 0.f, 0.f, 0.f};
        sacc[mf][nf] = z;
      }
    const char* Kl = (const char*)Ks[buf];
    __builtin_amdgcn_s_setprio(1);
#pragma unroll
    for (int kt = 0; kt < 2; ++kt) {
#pragma unroll
      for (int nf = 0; nf < 4; ++nf) {
        int key = l15 + nf * 16;
        bf16x8 kf = *(const bf16x8*)(Kl + (key << 7) +
                     (((kt << 6) + (lg << 4)) ^ ((key & 7) << 4)));
        sacc[0][nf] = __builtin_amdgcn_mfma_f32_16x16x32_bf16(qf[0][kt], kf, sacc[0][nf], 0, 0, 0);
        sacc[1][nf] = __builtin_amdgcn_mfma_f32_16x16x32_bf16(qf[1][kt], kf, sacc[1][nf], 0, 0, 0);
      }
    }
    __builtin_amdgcn_s_setprio(0);

    // ---- fixed-shift exp2 softmax: p = exp2(qk*C1 + tors) (no max/rescale)
    //      P -> per-wave LDS, key-pairs packed via v_cvt_pk_bf16_f32.
#pragma unroll
    for (int mf = 0; mf < 2; ++mf)
#pragma unroll
      for (int r = 0; r < 4; ++r) {
        int ql = wq * 32 + mf * 16 + lg * 4 + r;
        int tb = 127 + kc + l15 - ql;
        float x0 = fmaf(sacc[mf][0][r], C1_SCALE, tors[tb]);
        float x1 = fmaf(sacc[mf][1][r], C1_SCALE, tors[tb + 16]);
        float x2 = fmaf(sacc[mf][2][r], C1_SCALE, tors[tb + 32]);
        float x3 = fmaf(sacc[mf][3][r], C1_SCALE, tors[tb + 48]);
        float p0 = __builtin_exp2f(x0);
        float p1 = __builtin_exp2f(x1);
        float p2 = __builtin_exp2f(x2);
        float p3 = __builtin_exp2f(x3);
        l_part[mf][r] += (p0 + p1) + (p2 + p3);
        unsigned u01, u23;
        asm("v_cvt_pk_bf16_f32 %0, %1, %2" : "=v"(u01) : "v"(p0), "v"(p1));
        asm("v_cvt_pk_bf16_f32 %0, %1, %2" : "=v"(u23) : "v"(p2), "v"(p3));
        int qrow = mf * 16 + lg * 4 + r;
        int rb = qrow << 7, sw = (qrow & 7) << 4;
        *(unsigned*)((char*)Pw + rb + (((l15 << 2) +  0) ^ sw)) = u01;
        *(unsigned*)((char*)Pw + rb + (((l15 << 2) + 64) ^ sw)) = u23;
      }

    // ---- PV (P and V both in paired-key position order -> dot unchanged)
    const char* Vl = (const char*)Vs[buf];
    __builtin_amdgcn_s_setprio(1);
#pragma unroll
    for (int kt = 0; kt < 2; ++kt) {
      int q0r = l15, q1r = 16 + l15;
      bf16x8 pf0 = *(const bf16x8*)((const char*)Pw + (q0r << 7) +
                    (((kt << 6) + (lg << 4)) ^ ((q0r & 7) << 4)));
      bf16x8 pf1 = *(const bf16x8*)((const char*)Pw + (q1r << 7) +
                    (((kt << 6) + (lg << 4)) ^ ((q1r & 7) << 4)));
#pragma unroll
      for (int nf = 0; nf < 4; ++nf) {
        int d = l15 + nf * 16;
        bf16x8 vf = *(const bf16x8*)(Vl + (d << 7) +
                     (((kt << 6) + (lg << 4)) ^ ((d & 7) << 4)));
        oacc[0][nf] = __builtin_amdgcn_mfma_f32_16x16x32_bf16(pf0, vf, oacc[0][nf], 0, 0, 0);
        oacc[1][nf] = __builtin_amdgcn_mfma_f32_16x16x32_bf16(pf1, vf, oacc[1][nf], 0, 0, 0);
      }
    }
    __builtin_amdgcn_s_setprio(0);

    if (tt < 31) {   // T14 write-late
      char* Kd = (char*)Ks[buf ^ 1];
      char* Vd = (char*)Vs[buf ^ 1];
      *(int4*)(Kd + sdst0) = kreg0;
      *(int4*)(Kd + sdst1) = kreg1;
      *(int4*)(Vd + sdst0) = vreg0;
      *(int4*)(Vd + sdst1) = vreg1;
    }
    __syncthreads();
  }

  // epilogue: one l-reduction per row, normalize, hi/lo bf16 split store
  size_t ebase = (size_t)(bh >> 4) * (2048u * 1024u) + (size_t)(bh & 15) * 64u;
#pragma unroll
  for (int mf = 0; mf < 2; ++mf)
#pragma unroll
    for (int r = 0; r < 4; ++r) {
      float ls = l_part[mf][r];
      ls += __shfl_xor(ls, 1, 64);
      ls += __shfl_xor(ls, 2, 64);
      ls += __shfl_xor(ls, 4, 64);
      ls += __shfl_xor(ls, 8, 64);
      float inv = 1.f / ls;
      int ql = wq * 32 + mf * 16 + lg * 4 + r;
      size_t roff = ebase + (size_t)(q0 + ql) * 1024u;
#pragma unroll
      for (int nf = 0; nf < 4; ++nf) {
        float v = oacc[mf][nf][r] * inv;
        unsigned short h = f2bf(v);
        Ahi[roff + l15 + nf * 16] = h;
        Alo[roff + l15 + nf * 16] = f2bf(v - bf2f(h));
      }
    }
}

// ---------------- fused 3-product split-bf16 out-projection ------------------
// C = Ahi@Woh + Alo@Woh + Ahi@Wol + bias  (single accumulator, one epilogue).
// 64KB single-buffered LDS (4 panels), 2-barrier loop, T14-overlapped loads.
__global__ __launch_bounds__(256, 2) void gemm_out3_k(
    const unsigned short* __restrict__ Ahi, const unsigned short* __restrict__ Alo,
    const unsigned short* __restrict__ Woh, const unsigned short* __restrict__ Wol,
    const float* __restrict__ bias, float* __restrict__ C)
{
  __shared__ unsigned short Ah[8192], Al[8192], Bh[8192], Bl[8192];  // 64KB

  const int t = threadIdx.x;
  const int l = t & 63, wq = t >> 6;
  const int l15 = l & 15, lg = l >> 4;
  const int wm = wq >> 1, wn = wq & 1;
  const int m0 = blockIdx.y << 7, n0 = blockIdx.x << 7;

  const int srow = t >> 3;
  const int scb = (t & 7) << 4;
  const int swz = (srow & 7) << 4;
  int dst[4];
#pragma unroll
  for (int it = 0; it < 4; ++it)
    dst[it] = (it * 32 + srow) * 128 + (scb ^ swz);
  const char* pAh = (const char*)Ahi + (size_t)(m0 + srow) * 2048u + (size_t)scb;
  const char* pAl = (const char*)Alo + (size_t)(m0 + srow) * 2048u + (size_t)scb;
  const char* pBh = (const char*)Woh + (size_t)(n0 + srow) * 2048u + (size_t)scb;
  const char* pBl = (const char*)Wol + (size_t)(n0 + srow) * 2048u + (size_t)scb;

  f32x4 acc[4][4];
#pragma unroll
  for (int mf = 0; mf < 4; ++mf)
#pragma unroll
    for (int nf = 0; nf < 4; ++nf) {
      f32x4 z = {0.f, 0.f, 0.f, 0.f};
      acc[mf][nf] = z;
    }

  int4 rah[4], ral[4], rbh[4], rbl[4];
#pragma unroll
  for (int it = 0; it < 4; ++it) {
    rah[it] = *(const int4*)(pAh + (size_t)it * 65536u);
    ral[it] = *(const int4*)(pAl + (size_t)it * 65536u);
    rbh[it] = *(const int4*)(pBh + (size_t)it * 65536u);
    rbl[it] = *(const int4*)(pBl + (size_t)it * 65536u);
  }
#pragma unroll
  for (int it = 0; it < 4; ++it) {
    *(int4*)((char*)Ah + dst[it]) = rah[it];
    *(int4*)((char*)Al + dst[it]) = ral[it];
    *(int4*)((char*)Bh + dst[it]) = rbh[it];
    *(int4*)((char*)Bl + dst[it]) = rbl[it];
  }
  __syncthreads();

  const int fswz = (l15 & 7) << 4;

  for (int tt = 0; tt < 16; ++tt) {
    if (tt < 15) {   // T14 issue-early (latency hides under MFMA below)
      const size_t ko = (size_t)(tt + 1) * 128u;
#pragma unroll
      for (int it = 0; it < 4; ++it) {
        rah[it] = *(const int4*)(pAh + (size_t)it * 65536u + ko);
        ral[it] = *(const int4*)(pAl + (size_t)it * 65536u + ko);
        rbh[it] = *(const int4*)(pBh + (size_t)it * 65536u + ko);
        rbl[it] = *(const int4*)(pBl + (size_t)it * 65536u + ko);
      }
    }
#pragma unroll
    for (int kt = 0; kt < 2; ++kt) {
      bf16x8 bh8[4], bl8[4];
#pragma unroll
      for (int nf = 0; nf < 4; ++nf) {
        int r = wn * 64 + nf * 16 + l15;
        bh8[nf] = *(const bf16x8*)((const char*)Bh + r * 128 + ((kt * 64 + lg * 16) ^ fswz));
        bl8[nf] = *(const bf16x8*)((const char*)Bl + r * 128 + ((kt * 64 + lg * 16) ^ fswz));
      }
#pragma unroll
      for (int mf = 0; mf < 4; ++mf) {
        int r = wm * 64 + mf * 16 + l15;
        bf16x8 ah8 = *(const bf16x8*)((const char*)Ah + r * 128 + ((kt * 64 + lg * 16) ^ fswz));
        bf16x8 al8 = *(const bf16x8*)((const char*)Al + r * 128 + ((kt * 64 + lg * 16) ^ fswz));
#pragma unroll
        for (int nf = 0; nf < 4; ++nf) {
          acc[mf][nf] = __builtin_amdgcn_mfma_f32_16x16x32_bf16(ah8, bh8[nf], acc[mf][nf], 0, 0, 0);
          acc[mf][nf] = __builtin_amdgcn_mfma_f32_16x16x32_bf16(al8, bh8[nf], acc[mf][nf], 0, 0, 0);
          acc[mf][nf] = __builtin_amdgcn_mfma_f32_16x16x32_bf16(ah8, bl8[nf], acc[mf][nf], 0, 0, 0);
        }
      }
    }
    __syncthreads();             // all waves done reading this K-slice
    if (tt < 15) {
#pragma unroll
      for (int it = 0; it < 4; ++it) {
        *(int4*)((char*)Ah + dst[it]) = rah[it];
        *(int4*)((char*)Al + dst[it]) = ral[it];
        *(int4*)((char*)Bh + dst[it]) = rbh[it];
        *(int4*)((char*)Bl + dst[it]) = rbl[it];
      }
      __syncthreads();           // writes visible before next compute
    }
  }

#pragma unroll
  for (int mf = 0; mf < 4; ++mf)
#pragma unroll
    for (int r = 0; r < 4; ++r) {
      const int m = m0 + wm * 64 + mf * 16 + lg * 4 + r;
#pragma unroll
      for (int nf = 0; nf < 4; ++nf) {
        const int n = n0 + wn * 64 + nf * 16 + l15;
        C[(size_t)m * 1024u + n] = acc[mf][nf][r] + bias[n];
      }
    }
}

// ---------------------------------------------------------------------------
extern "C" void kernel_launch(void* const* d_in, const int* in_sizes, int n_in,
                              void* d_out, int out_size, void* d_ws, size_t ws_size,
                              hipStream_t stream) {
  (void)in_sizes; (void)n_in; (void)out_size; (void)ws_size;
  const float* hs = (const float*)d_in[0];
  const float* Wq = (const float*)d_in[1];
  const float* bq = (const float*)d_in[2];
  const float* Wk = (const float*)d_in[3];
  const float* bk = (const float*)d_in[4];
  const float* Wv = (const float*)d_in[5];
  const float* bv = (const float*)d_in[6];
  const float* Wo = (const float*)d_in[7];
  const float* bo = (const float*)d_in[8];
  float* out = (float*)d_out;

  // ws: tab | hs_bf 8MB | Wqt,Wkt,Wvt (contiguous 6MB) | Woh,Wol 2MB ea
  //     | Qbf,Kbf (contiguous 16MB) | Vtg 8MB | Ahi,Alo 8MB ea
  float* ws = (float*)d_ws;
  float* tab = ws;
  unsigned short* hs_bf = (unsigned short*)(ws + 4096);
  unsigned short* Wqt = hs_bf + 4194304u;
  unsigned short* Wkt = Wqt + 1048576u;
  unsigned short* Wvt = Wkt + 1048576u;
  unsigned short* Woh = Wvt + 1048576u;
  unsigned short* Wol = Woh + 1048576u;
  unsigned short* Qbf = Wol + 1048576u;
  unsigned short* Kbf = Qbf + 4194304u;
  unsigned short* Vtg = Kbf + 4194304u;
  unsigned short* Ahi = Vtg + 4194304u;
  unsigned short* Alo = Ahi + 4194304u;

  tor_table_k<<<16, 256, 0, stream>>>(tab);
  cast_hs_k<<<2048, 256, 0, stream>>>(hs, hs_bf);
  dim3 gc(16, 32);
  cast_wt_k<false><<<gc, 256, 0, stream>>>(Wq, Wqt, nullptr);
  cast_wt_k<false><<<gc, 256, 0, stream>>>(Wk, Wkt, nullptr);
  cast_wt_k<false><<<gc, 256, 0, stream>>>(Wv, Wvt, nullptr);
  cast_wt_k<true ><<<gc, 256, 0, stream>>>(Wo, Woh, Wol);

  gemm_qkv_k<<<dim3(24, 32), 256, 0, stream>>>(hs_bf, Wqt, bq, bk, bv, Qbf, Vtg);

  attn_mfma_k<<<dim3(16, 32), 256, 0, stream>>>(Qbf, Kbf, Vtg, tab, Ahi, Alo);

  gemm_out3_k<<<dim3(8, 32), 256, 0, stream>>>(Ahi, Alo, Woh, Wol, bo, out);
}

// Round 12
// 247.905 us; speedup vs baseline: 4.7366x; 1.3315x over previous
//
#include <hip/hip_runtime.h>
#include <math.h>

// ---------------------------------------------------------------------------
// HodgeTorsionAttention R12:
//   casts -> fused QKV bf16 MFMA GEMM (XCD-chunked) -> bf16 MFMA flash attn
//   (fixed-shift exp2 softmax) -> single-pass bf16 MFMA out-projection
//   (split-bf16 dropped: measured absmax is attention-dominated).
// B=2, S=2048, D=1024, H=16, hd=64.
// ---------------------------------------------------------------------------

typedef __attribute__((ext_vector_type(8))) short bf16x8;   // 8 bf16 = 4 VGPR
typedef __attribute__((ext_vector_type(4))) float f32x4;    // MFMA acc

__device__ __forceinline__ unsigned short f2bf(float f) {   // RNE f32->bf16
  unsigned u = __float_as_uint(f);
  return (unsigned short)((u + 0x7FFFu + ((u >> 16) & 1u)) >> 16);
}
__device__ __forceinline__ int pack2(unsigned short a, unsigned short b) {
  return (int)(((unsigned)b << 16) | (unsigned)a);
}

// C1 = 0.125 * log2(e): folds the 1/sqrt(hd) scale and the exp->exp2 change.
#define C1_SCALE 0.18033688011112042f

// -------- torsion table (pre-folded): tab[i] = tor(i-2047)*log2e - 8*log2e --
__global__ __launch_bounds__(256) void tor_table_k(float* __restrict__ tab) {
  int i = blockIdx.x * 256 + threadIdx.x;
  if (i < 4096) {
    double delta = (double)(i - 2047);
    double giza = 51.85 * M_PI / 180.0;
    double l2e = 1.4426950408889634;
    tab[i] = (float)((1.618033988749895 * sin(giza * delta)) * l2e - 8.0 * l2e);
  }
}

// ---------------- cast hs [4096][1024] f32 -> bf16 row-major ----------------
__global__ __launch_bounds__(256) void cast_hs_k(const float* __restrict__ X,
                                                 unsigned short* __restrict__ Y) {
  int i = (blockIdx.x * 256 + threadIdx.x) * 8;
  float4 a = *(const float4*)&X[i];
  float4 b = *(const float4*)&X[i + 4];
  int4 o;
  o.x = pack2(f2bf(a.x), f2bf(a.y));
  o.y = pack2(f2bf(a.z), f2bf(a.w));
  o.z = pack2(f2bf(b.x), f2bf(b.y));
  o.w = pack2(f2bf(b.z), f2bf(b.w));
  *(int4*)&Y[i] = o;
}

// ---------------- transpose-cast W [1024 k][1024 n] -> Wt [n][k] bf16 -------
__global__ __launch_bounds__(256) void cast_wt_k(const float* __restrict__ W,
                                                 unsigned short* __restrict__ Th) {
  const int lane = threadIdx.x & 63, w = threadIdx.x >> 6;
  const int n = blockIdx.x * 64 + lane;
  const int k0 = blockIdx.y * 32 + w * 8;
  float v[8];
#pragma unroll
  for (int j = 0; j < 8; ++j) v[j] = W[(size_t)(k0 + j) * 1024u + n];
  unsigned short h[8];
#pragma unroll
  for (int j = 0; j < 8; ++j) h[j] = f2bf(v[j]);
  int4 hp;
  hp.x = pack2(h[0], h[1]); hp.y = pack2(h[2], h[3]);
  hp.z = pack2(h[4], h[5]); hp.w = pack2(h[6], h[7]);
  *(int4*)&Th[(size_t)n * 1024u + k0] = hp;
}

// ---------------- fused QKV bf16 MFMA GEMM (XCD m-chunked) ------------------
// grid 1D 768. sw = (bid&7)*96 + bid>>3: each XCD gets 4 contiguous m-rows
// (A panels L2-resident per XCD). mrow = sw/24; r = sw%24; third = r>>3.
// Q,K -> head-split [bh][tok][64]; V -> [bh][64][2048] paired-key permuted.
__global__ __launch_bounds__(256) void gemm_qkv_k(
    const unsigned short* __restrict__ A, const unsigned short* __restrict__ Wt3,
    const float* __restrict__ bq, const float* __restrict__ bk,
    const float* __restrict__ bv,
    unsigned short* __restrict__ QK, unsigned short* __restrict__ Vt)
{
  __shared__ unsigned short Asw[2][8192];  // [128 m][64 k] swizzled
  __shared__ unsigned short Bsw[2][8192];  // [128 n][64 k] swizzled

  const int t = threadIdx.x;
  const int l = t & 63, wq = t >> 6;
  const int l15 = l & 15, lg = l >> 4;
  const int wm = wq >> 1, wn = wq & 1;
  const int bid = blockIdx.x;
  const int sw = ((bid & 7) * 96) + (bid >> 3);   // bijective, 768%8==0
  const int m0 = (sw / 24) << 7;
  const int rr = sw % 24;
  const int third = rr >> 3;
  const int n0 = (rr & 7) << 7;

  const int srow = t >> 3;
  const int scb = (t & 7) << 4;
  const int swz = (srow & 7) << 4;
  int dst[4];
#pragma unroll
  for (int it = 0; it < 4; ++it)
    dst[it] = (it * 32 + srow) * 128 + (scb ^ swz);
  const char* Ap = (const char*)A + (size_t)(m0 + srow) * 2048u + (size_t)scb;
  const char* Bp = (const char*)Wt3 + (size_t)third * 2097152u +
                   (size_t)(n0 + srow) * 2048u + (size_t)scb;

  f32x4 acc[4][4];
#pragma unroll
  for (int mf = 0; mf < 4; ++mf)
#pragma unroll
    for (int nf = 0; nf < 4; ++nf) {
      f32x4 z = {0.f, 0.f, 0.f, 0.f};
      acc[mf][nf] = z;
    }

  int4 ra[4], rb[4];
#pragma unroll
  for (int it = 0; it < 4; ++it) {
    ra[it] = *(const int4*)(Ap + (size_t)it * 65536u);
    rb[it] = *(const int4*)(Bp + (size_t)it * 65536u);
  }
#pragma unroll
  for (int it = 0; it < 4; ++it) {
    *(int4*)((char*)Asw[0] + dst[it]) = ra[it];
    *(int4*)((char*)Bsw[0] + dst[it]) = rb[it];
  }
  __syncthreads();

  const int fswz = (l15 & 7) << 4;

  for (int tt = 0; tt < 16; ++tt) {
    const int buf = tt & 1;
    if (tt < 15) {                       // T14 issue-early next K-slice
      const size_t ko = (size_t)(tt + 1) * 128u;
#pragma unroll
      for (int it = 0; it < 4; ++it) {
        ra[it] = *(const int4*)(Ap + (size_t)it * 65536u + ko);
        rb[it] = *(const int4*)(Bp + (size_t)it * 65536u + ko);
      }
    }
    const char* Al = (const char*)Asw[buf];
    const char* Bl = (const char*)Bsw[buf];
#pragma unroll
    for (int kt = 0; kt < 2; ++kt) {
      bf16x8 af[4], bfr[4];
#pragma unroll
      for (int mf = 0; mf < 4; ++mf) {
        int r = wm * 64 + mf * 16 + l15;
        af[mf] = *(const bf16x8*)(Al + r * 128 + ((kt * 64 + lg * 16) ^ fswz));
      }
#pragma unroll
      for (int nf = 0; nf < 4; ++nf) {
        int r = wn * 64 + nf * 16 + l15;
        bfr[nf] = *(const bf16x8*)(Bl + r * 128 + ((kt * 64 + lg * 16) ^ fswz));
      }
#pragma unroll
      for (int mf = 0; mf < 4; ++mf)
#pragma unroll
        for (int nf = 0; nf < 4; ++nf)
          acc[mf][nf] = __builtin_amdgcn_mfma_f32_16x16x32_bf16(af[mf], bfr[nf],
                                                                acc[mf][nf], 0, 0, 0);
    }
    if (tt < 15) {                       // T14 write-late into other buffer
      char* Ad = (char*)Asw[buf ^ 1];
      char* Bd = (char*)Bsw[buf ^ 1];
#pragma unroll
      for (int it = 0; it < 4; ++it) {
        *(int4*)(Ad + dst[it]) = ra[it];
        *(int4*)(Bd + dst[it]) = rb[it];
      }
    }
    __syncthreads();
  }

  const float* bs = (third == 0) ? bq : (third == 1) ? bk : bv;
  unsigned short* QKb = QK + (size_t)third * 4194304u;   // valid for third<2
#pragma unroll
  for (int mf = 0; mf < 4; ++mf)
#pragma unroll
    for (int r = 0; r < 4; ++r) {
      const int m = m0 + wm * 64 + mf * 16 + lg * 4 + r;
      const int bsel = m >> 11, tok = m & 2047;
#pragma unroll
      for (int nf = 0; nf < 4; ++nf) {
        const int nl = n0 + wn * 64 + nf * 16 + l15;
        float v = acc[mf][nf][r] + bs[nl];
        const int h = nl >> 6, d = nl & 63;
        if (third < 2) {
          QKb[(size_t)((bsel << 4) + h) * 131072u + (size_t)tok * 64u + d] = f2bf(v);
        } else {
          int lk = tok & 31;
          int pos = (lk < 16) ? (lk << 1) : (((lk - 16) << 1) | 1);
          int tokp = (tok & ~31) | pos;
          Vt[(size_t)((bsel << 4) + h) * 131072u + (size_t)d * 2048u + tokp] = f2bf(v);
        }
      }
    }
}

// ---------------- bf16 MFMA flash attention (fixed-shift softmax) -----------
// grid 1D 512, XCD bh-chunked: sw = (bid&7)*64 + bid>>3; bh = sw>>4 (4 bh per
// XCD -> K/V panels L2-resident), q0 = (sw&15)<<7.
__global__ __launch_bounds__(256) void attn_mfma_k(
    const unsigned short* __restrict__ Qb, const unsigned short* __restrict__ Kb,
    const unsigned short* __restrict__ Vtg, const float* __restrict__ tab,
    unsigned short* __restrict__ Ahi)
{
  __shared__ unsigned short Ks[2][4096];  // [64 key][64 dim] swizzled
  __shared__ unsigned short Vs[2][4096];  // [64 dim][64 key-pos] swizzled
  __shared__ unsigned short Ps[4][2048];  // per-wave [32 q][64 key-pos] swizzled
  __shared__ float tors[2176];            // pre-folded

  const int t  = threadIdx.x;
  const int l  = t & 63;
  const int wq = t >> 6;
  const int l15 = l & 15, lg = l >> 4;
  const int bid = blockIdx.x;
  const int swb = ((bid & 7) << 6) + (bid >> 3);  // bijective, 512%8==0
  const int q0 = (swb & 15) << 7;
  const int bh = swb >> 4;

  for (int x = t; x < 2176; x += 256) tors[x] = tab[1920 - q0 + x];

  const unsigned short* Qp = Qb + (size_t)bh * 131072u;
  const char* Kpanel = (const char*)(Kb  + (size_t)bh * 131072u);
  const char* Vpanel = (const char*)(Vtg + (size_t)bh * 131072u);

  bf16x8 qf[2][2];
#pragma unroll
  for (int mf = 0; mf < 2; ++mf)
#pragma unroll
    for (int kt = 0; kt < 2; ++kt) {
      int tok = q0 + wq * 32 + mf * 16 + l15;
      qf[mf][kt] = *(const bf16x8*)&Qp[(size_t)tok * 64u + (size_t)(kt * 32 + lg * 8)];
    }

  f32x4 oacc[2][4];
  float l_part[2][4];
#pragma unroll
  for (int mf = 0; mf < 2; ++mf)
#pragma unroll
    for (int r = 0; r < 4; ++r) {
      l_part[mf][r] = 0.f;
      f32x4 z = {0.f, 0.f, 0.f, 0.f};
      oacc[mf][r] = z;
    }

  const int sb    = (wq * 2) * 1024 + l * 16;
  const int srow0 = sb >> 7,          scol0 = sb & 127;
  const int srow1 = (sb + 1024) >> 7, scol1 = (sb + 1024) & 127;
  const int sdst0 = srow0 * 128 + (scol0 ^ ((srow0 & 7) << 4));
  const int sdst1 = srow1 * 128 + (scol1 ^ ((srow1 & 7) << 4));

  int4 kreg0, kreg1, vreg0, vreg1;
  kreg0 = *(const int4*)(Kpanel + sb);
  kreg1 = *(const int4*)(Kpanel + sb + 1024);
  vreg0 = *(const int4*)(Vpanel + (size_t)srow0 * 4096u + (size_t)scol0);
  vreg1 = *(const int4*)(Vpanel + (size_t)srow1 * 4096u + (size_t)scol1);
  *(int4*)((char*)Ks[0] + sdst0) = kreg0;
  *(int4*)((char*)Ks[0] + sdst1) = kreg1;
  *(int4*)((char*)Vs[0] + sdst0) = vreg0;
  *(int4*)((char*)Vs[0] + sdst1) = vreg1;
  __syncthreads();

  unsigned short* Pw = Ps[wq];

  for (int tt = 0; tt < 32; ++tt) {
    const int buf = tt & 1;
    const int kc  = tt << 6;

    if (tt < 31) {   // T14 issue-early
      const char* kp = Kpanel + (tt + 1) * 8192;
      kreg0 = *(const int4*)(kp + sb);
      kreg1 = *(const int4*)(kp + sb + 1024);
      const char* vp = Vpanel + (tt + 1) * 128;
      vreg0 = *(const int4*)(vp + (size_t)srow0 * 4096u + (size_t)scol0);
      vreg1 = *(const int4*)(vp + (size_t)srow1 * 4096u + (size_t)scol1);
    }

    // ---- QK^T
    f32x4 sacc[2][4];
#pragma unroll
    for (int mf = 0; mf < 2; ++mf)
#pragma unroll
      for (int nf = 0; nf < 4; ++nf) {
        f32x4 z = {0.f, 0.f, 0.f, 0.f};
        sacc[mf][nf] = z;
      }
    const char* Kl = (const char*)Ks[buf];
    __builtin_amdgcn_s_setprio(1);
#pragma unroll
    for (int kt = 0; kt < 2; ++kt) {
#pragma unroll
      for (int nf = 0; nf < 4; ++nf) {
        int key = l15 + nf * 16;
        bf16x8 kf = *(const bf16x8*)(Kl + (key << 7) +
                     (((kt << 6) + (lg << 4)) ^ ((key & 7) << 4)));
        sacc[0][nf] = __builtin_amdgcn_mfma_f32_16x16x32_bf16(qf[0][kt], kf, sacc[0][nf], 0, 0, 0);
        sacc[1][nf] = __builtin_amdgcn_mfma_f32_16x16x32_bf16(qf[1][kt], kf, sacc[1][nf], 0, 0, 0);
      }
    }
    __builtin_amdgcn_s_setprio(0);

    // ---- fixed-shift exp2 softmax; P pairs packed via v_cvt_pk_bf16_f32
#pragma unroll
    for (int mf = 0; mf < 2; ++mf)
#pragma unroll
      for (int r = 0; r < 4; ++r) {
        int ql = wq * 32 + mf * 16 + lg * 4 + r;
        int tb = 127 + kc + l15 - ql;
        float x0 = fmaf(sacc[mf][0][r], C1_SCALE, tors[tb]);
        float x1 = fmaf(sacc[mf][1][r], C1_SCALE, tors[tb + 16]);
        float x2 = fmaf(sacc[mf][2][r], C1_SCALE, tors[tb + 32]);
        float x3 = fmaf(sacc[mf][3][r], C1_SCALE, tors[tb + 48]);
        float p0 = __builtin_exp2f(x0);
        float p1 = __builtin_exp2f(x1);
        float p2 = __builtin_exp2f(x2);
        float p3 = __builtin_exp2f(x3);
        l_part[mf][r] += (p0 + p1) + (p2 + p3);
        unsigned u01, u23;
        asm("v_cvt_pk_bf16_f32 %0, %1, %2" : "=v"(u01) : "v"(p0), "v"(p1));
        asm("v_cvt_pk_bf16_f32 %0, %1, %2" : "=v"(u23) : "v"(p2), "v"(p3));
        int qrow = mf * 16 + lg * 4 + r;
        int rb = qrow << 7, sw = (qrow & 7) << 4;
        *(unsigned*)((char*)Pw + rb + (((l15 << 2) +  0) ^ sw)) = u01;
        *(unsigned*)((char*)Pw + rb + (((l15 << 2) + 64) ^ sw)) = u23;
      }

    // ---- PV (paired-key position order in both P and V)
    const char* Vl = (const char*)Vs[buf];
    __builtin_amdgcn_s_setprio(1);
#pragma unroll
    for (int kt = 0; kt < 2; ++kt) {
      int q0r = l15, q1r = 16 + l15;
      bf16x8 pf0 = *(const bf16x8*)((const char*)Pw + (q0r << 7) +
                    (((kt << 6) + (lg << 4)) ^ ((q0r & 7) << 4)));
      bf16x8 pf1 = *(const bf16x8*)((const char*)Pw + (q1r << 7) +
                    (((kt << 6) + (lg << 4)) ^ ((q1r & 7) << 4)));
#pragma unroll
      for (int nf = 0; nf < 4; ++nf) {
        int d = l15 + nf * 16;
        bf16x8 vf = *(const bf16x8*)(Vl + (d << 7) +
                     (((kt << 6) + (lg << 4)) ^ ((d & 7) << 4)));
        oacc[0][nf] = __builtin_amdgcn_mfma_f32_16x16x32_bf16(pf0, vf, oacc[0][nf], 0, 0, 0);
        oacc[1][nf] = __builtin_amdgcn_mfma_f32_16x16x32_bf16(pf1, vf, oacc[1][nf], 0, 0, 0);
      }
    }
    __builtin_amdgcn_s_setprio(0);

    if (tt < 31) {   // T14 write-late
      char* Kd = (char*)Ks[buf ^ 1];
      char* Vd = (char*)Vs[buf ^ 1];
      *(int4*)(Kd + sdst0) = kreg0;
      *(int4*)(Kd + sdst1) = kreg1;
      *(int4*)(Vd + sdst0) = vreg0;
      *(int4*)(Vd + sdst1) = vreg1;
    }
    __syncthreads();
  }

  // epilogue: one l-reduction per row, normalize, bf16 store (hi only)
  size_t ebase = (size_t)(bh >> 4) * (2048u * 1024u) + (size_t)(bh & 15) * 64u;
#pragma unroll
  for (int mf = 0; mf < 2; ++mf)
#pragma unroll
    for (int r = 0; r < 4; ++r) {
      float ls = l_part[mf][r];
      ls += __shfl_xor(ls, 1, 64);
      ls += __shfl_xor(ls, 2, 64);
      ls += __shfl_xor(ls, 4, 64);
      ls += __shfl_xor(ls, 8, 64);
      float inv = 1.f / ls;
      int ql = wq * 32 + mf * 16 + lg * 4 + r;
      size_t roff = ebase + (size_t)(q0 + ql) * 1024u;
#pragma unroll
      for (int nf = 0; nf < 4; ++nf)
        Ahi[roff + l15 + nf * 16] = f2bf(oacc[mf][nf][r] * inv);
    }
}

// ---------------- single-pass bf16 MFMA out-projection (R7-validated) -------
// C[4096,1024] = A @ Wot^T + bias, fp32 out. XCD m-chunked: sw=(bid&7)*32+bid/8.
__global__ __launch_bounds__(256) void gemm_out_k(
    const unsigned short* __restrict__ A, const unsigned short* __restrict__ Bt,
    const float* __restrict__ bias, float* __restrict__ C)
{
  __shared__ unsigned short Asw[2][8192];
  __shared__ unsigned short Bsw[2][8192];

  const int t = threadIdx.x;
  const int l = t & 63, wq = t >> 6;
  const int l15 = l & 15, lg = l >> 4;
  const int wm = wq >> 1, wn = wq & 1;
  const int bid = blockIdx.x;
  const int sw = ((bid & 7) << 5) + (bid >> 3);   // bijective, 256%8==0
  const int n0 = (sw & 7) << 7, m0 = (sw >> 3) << 7;

  const int srow = t >> 3;
  const int scb = (t & 7) << 4;
  const int swz = (srow & 7) << 4;
  int dst[4];
#pragma unroll
  for (int it = 0; it < 4; ++it)
    dst[it] = (it * 32 + srow) * 128 + (scb ^ swz);
  const char* Ap = (const char*)A + (size_t)(m0 + srow) * 2048u + (size_t)scb;
  const char* Bp = (const char*)Bt + (size_t)(n0 + srow) * 2048u + (size_t)scb;

  f32x4 acc[4][4];
#pragma unroll
  for (int mf = 0; mf < 4; ++mf)
#pragma unroll
    for (int nf = 0; nf < 4; ++nf) {
      f32x4 z = {0.f, 0.f, 0.f, 0.f};
      acc[mf][nf] = z;
    }

  int4 ra[4], rb[4];
#pragma unroll
  for (int it = 0; it < 4; ++it) {
    ra[it] = *(const int4*)(Ap + (size_t)it * 65536u);
    rb[it] = *(const int4*)(Bp + (size_t)it * 65536u);
  }
#pragma unroll
  for (int it = 0; it < 4; ++it) {
    *(int4*)((char*)Asw[0] + dst[it]) = ra[it];
    *(int4*)((char*)Bsw[0] + dst[it]) = rb[it];
  }
  __syncthreads();

  const int fswz = (l15 & 7) << 4;

  for (int tt = 0; tt < 16; ++tt) {
    const int buf = tt & 1;
    if (tt < 15) {
      const size_t ko = (size_t)(tt + 1) * 128u;
#pragma unroll
      for (int it = 0; it < 4; ++it) {
        ra[it] = *(const int4*)(Ap + (size_t)it * 65536u + ko);
        rb[it] = *(const int4*)(Bp + (size_t)it * 65536u + ko);
      }
    }
    const char* Al = (const char*)Asw[buf];
    const char* Bl = (const char*)Bsw[buf];
#pragma unroll
    for (int kt = 0; kt < 2; ++kt) {
      bf16x8 af[4], bfr[4];
#pragma unroll
      for (int mf = 0; mf < 4; ++mf) {
        int r = wm * 64 + mf * 16 + l15;
        af[mf] = *(const bf16x8*)(Al + r * 128 + ((kt * 64 + lg * 16) ^ fswz));
      }
#pragma unroll
      for (int nf = 0; nf < 4; ++nf) {
        int r = wn * 64 + nf * 16 + l15;
        bfr[nf] = *(const bf16x8*)(Bl + r * 128 + ((kt * 64 + lg * 16) ^ fswz));
      }
#pragma unroll
      for (int mf = 0; mf < 4; ++mf)
#pragma unroll
        for (int nf = 0; nf < 4; ++nf)
          acc[mf][nf] = __builtin_amdgcn_mfma_f32_16x16x32_bf16(af[mf], bfr[nf],
                                                                acc[mf][nf], 0, 0, 0);
    }
    if (tt < 15) {
      char* Ad = (char*)Asw[buf ^ 1];
      char* Bd = (char*)Bsw[buf ^ 1];
#pragma unroll
      for (int it = 0; it < 4; ++it) {
        *(int4*)(Ad + dst[it]) = ra[it];
        *(int4*)(Bd + dst[it]) = rb[it];
      }
    }
    __syncthreads();
  }

#pragma unroll
  for (int mf = 0; mf < 4; ++mf)
#pragma unroll
    for (int r = 0; r < 4; ++r) {
      const int m = m0 + wm * 64 + mf * 16 + lg * 4 + r;
#pragma unroll
      for (int nf = 0; nf < 4; ++nf) {
        const int n = n0 + wn * 64 + nf * 16 + l15;
        C[(size_t)m * 1024u + n] = acc[mf][nf][r] + bias[n];
      }
    }
}

// ---------------------------------------------------------------------------
extern "C" void kernel_launch(void* const* d_in, const int* in_sizes, int n_in,
                              void* d_out, int out_size, void* d_ws, size_t ws_size,
                              hipStream_t stream) {
  (void)in_sizes; (void)n_in; (void)out_size; (void)ws_size;
  const float* hs = (const float*)d_in[0];
  const float* Wq = (const float*)d_in[1];
  const float* bq = (const float*)d_in[2];
  const float* Wk = (const float*)d_in[3];
  const float* bk = (const float*)d_in[4];
  const float* Wv = (const float*)d_in[5];
  const float* bv = (const float*)d_in[6];
  const float* Wo = (const float*)d_in[7];
  const float* bo = (const float*)d_in[8];
  float* out = (float*)d_out;

  // ws: tab | hs_bf 8MB | Wqt,Wkt,Wvt (contig 6MB) | Wot 2MB | Qbf,Kbf (contig)
  //     | Vtg 8MB | Ahi 8MB   (~48 MB)
  float* ws = (float*)d_ws;
  float* tab = ws;
  unsigned short* hs_bf = (unsigned short*)(ws + 4096);
  unsigned short* Wqt = hs_bf + 4194304u;
  unsigned short* Wkt = Wqt + 1048576u;
  unsigned short* Wvt = Wkt + 1048576u;
  unsigned short* Wot = Wvt + 1048576u;
  unsigned short* Qbf = Wot + 1048576u;
  unsigned short* Kbf = Qbf + 4194304u;
  unsigned short* Vtg = Kbf + 4194304u;
  unsigned short* Ahi = Vtg + 4194304u;

  tor_table_k<<<16, 256, 0, stream>>>(tab);
  cast_hs_k<<<2048, 256, 0, stream>>>(hs, hs_bf);
  dim3 gc(16, 32);
  cast_wt_k<<<gc, 256, 0, stream>>>(Wq, Wqt);
  cast_wt_k<<<gc, 256, 0, stream>>>(Wk, Wkt);
  cast_wt_k<<<gc, 256, 0, stream>>>(Wv, Wvt);
  cast_wt_k<<<gc, 256, 0, stream>>>(Wo, Wot);

  gemm_qkv_k<<<768, 256, 0, stream>>>(hs_bf, Wqt, bq, bk, bv, Qbf, Vtg);

  attn_mfma_k<<<512, 256, 0, stream>>>(Qbf, Kbf, Vtg, tab, Ahi);

  gemm_out_k<<<256, 256, 0, stream>>>(Ahi, Wot, bo, out);
}